// Round 1
// baseline (4712.481 us; speedup 1.0000x reference)
//
#include <hip/hip_runtime.h>
#include <hip/hip_bf16.h>

#define DEPTH 6
#define E 1024
#define H 16
#define S 2048
#define V 32000
#define BB 2
#define HD 64
#define NTOK (BB * S)  // 4096

typedef __attribute__((ext_vector_type(8))) short bf16x8;
typedef __attribute__((ext_vector_type(4))) float f32x4;

__device__ inline unsigned short f2bf(float f) {
    union { float f; unsigned u; } v; v.f = f;
    unsigned r = v.u + 0x7fff + ((v.u >> 16) & 1);
    return (unsigned short)(r >> 16);
}

// ---------------------------------------------------------------- embedding
__global__ void embed_kernel(const int* __restrict__ idx, const float* __restrict__ tok,
                             const float* __restrict__ pos, float* __restrict__ x) {
    int t = blockIdx.x;             // token 0..NTOK-1
    int s = t & (S - 1);
    int tokid = idx[t];
    int c = threadIdx.x * 4;        // 256 threads * 4 = 1024
    float4 a = *(const float4*)&tok[(size_t)tokid * E + c];
    float4 p = *(const float4*)&pos[(size_t)s * E + c];
    float4 o; o.x = a.x + p.x; o.y = a.y + p.y; o.z = a.z + p.z; o.w = a.w + p.w;
    *(float4*)&x[(size_t)t * E + c] = o;
}

// ---------------------------------------------------------------- layernorm (f32 in, bf16 out)
__global__ __launch_bounds__(256) void ln_kernel(const float* __restrict__ x,
                                                 const float* __restrict__ w,
                                                 const float* __restrict__ b,
                                                 unsigned short* __restrict__ out) {
    int row = blockIdx.x;
    int tid = threadIdx.x;
    int c = tid * 4;
    float4 v = *(const float4*)&x[(size_t)row * E + c];
    float s  = v.x + v.y + v.z + v.w;
    float sq = v.x * v.x + v.y * v.y + v.z * v.z + v.w * v.w;
    __shared__ float red[8];
    for (int o = 32; o > 0; o >>= 1) { s += __shfl_xor(s, o); sq += __shfl_xor(sq, o); }
    int wave = tid >> 6, lane = tid & 63;
    if (lane == 0) { red[wave] = s; red[4 + wave] = sq; }
    __syncthreads();
    if (tid == 0) {
        red[0] = red[0] + red[1] + red[2] + red[3];
        red[4] = red[4] + red[5] + red[6] + red[7];
    }
    __syncthreads();
    float mean = red[0] * (1.0f / E);
    float var  = red[4] * (1.0f / E) - mean * mean;
    float rstd = rsqrtf(var + 1e-5f);
    float4 wv = *(const float4*)&w[c];
    float4 bv = *(const float4*)&b[c];
    unsigned a0 = f2bf((v.x - mean) * rstd * wv.x + bv.x);
    unsigned a1 = f2bf((v.y - mean) * rstd * wv.y + bv.y);
    unsigned a2 = f2bf((v.z - mean) * rstd * wv.z + bv.z);
    unsigned a3 = f2bf((v.w - mean) * rstd * wv.w + bv.w);
    uint2 o; o.x = a0 | (a1 << 16); o.y = a2 | (a3 << 16);
    *(uint2*)&out[(size_t)row * E + c] = o;
}

// ---------------------------------------------------------------- GEMM: C = A(bf16,[M][K]) * Bw(f32,[N][K])^T
template <int OUT_BF16, int ACT_GELU, int HAS_BIAS, int HAS_RES>
__global__ __launch_bounds__(256) void gemm_kernel(const unsigned short* __restrict__ A,
                                                   const float* __restrict__ Bw,
                                                   const float* __restrict__ bias,
                                                   const float* __restrict__ res,
                                                   void* __restrict__ outp,
                                                   int M, int N, int K) {
    __shared__ unsigned short As[128][40];  // +8 pad: bank-friendly, keeps 16B align
    __shared__ unsigned short Bs[128][40];
    int tid = threadIdx.x;
    int bm = blockIdx.y * 128, bn = blockIdx.x * 128;
    int wave = tid >> 6, lane = tid & 63;
    int wr = wave >> 1, wc = wave & 1;
    int l15 = lane & 15, g4 = lane >> 4;
    f32x4 acc[4][4] = {};

    for (int k0 = 0; k0 < K; k0 += 32) {
        // stage A tile 128x32 bf16 (copy bits)
        #pragma unroll
        for (int p = 0; p < 2; p++) {
            int idx = tid + p * 256;
            int row = idx >> 2, c8 = (idx & 3) * 8;
            uint4 v = *(const uint4*)&A[(size_t)(bm + row) * K + k0 + c8];
            *(uint4*)&As[row][c8] = v;
        }
        // stage B tile 128x32: f32 -> bf16
        #pragma unroll
        for (int p = 0; p < 4; p++) {
            int idx = tid + p * 256;
            int row = idx >> 3, c4 = (idx & 7) * 4;
            float4 v = *(const float4*)&Bw[(size_t)(bn + row) * K + k0 + c4];
            ushort4 o; o.x = f2bf(v.x); o.y = f2bf(v.y); o.z = f2bf(v.z); o.w = f2bf(v.w);
            *(ushort4*)&Bs[row][c4] = o;
        }
        __syncthreads();
        bf16x8 a[4], bfr[4];
        #pragma unroll
        for (int m = 0; m < 4; m++) a[m] = *(const bf16x8*)&As[wr * 64 + m * 16 + l15][8 * g4];
        #pragma unroll
        for (int n = 0; n < 4; n++) bfr[n] = *(const bf16x8*)&Bs[wc * 64 + n * 16 + l15][8 * g4];
        #pragma unroll
        for (int m = 0; m < 4; m++)
            #pragma unroll
            for (int n = 0; n < 4; n++)
                acc[m][n] = __builtin_amdgcn_mfma_f32_16x16x32_bf16(a[m], bfr[n], acc[m][n], 0, 0, 0);
        __syncthreads();
    }

    float* outf = (float*)outp;
    unsigned short* outb = (unsigned short*)outp;
    #pragma unroll
    for (int m = 0; m < 4; m++)
        #pragma unroll
        for (int n = 0; n < 4; n++)
            #pragma unroll
            for (int j = 0; j < 4; j++) {
                int r = bm + wr * 64 + m * 16 + g4 * 4 + j;
                int c = bn + wc * 64 + n * 16 + l15;
                float v = acc[m][n][j];
                if (HAS_BIAS) v += bias[c];
                if (ACT_GELU) v = 0.5f * v * (1.0f + erff(v * 0.70710678118f));
                if (HAS_RES) v += res[(size_t)r * N + c];
                if (OUT_BF16) outb[(size_t)r * N + c] = f2bf(v);
                else outf[(size_t)r * N + c] = v;
            }
}

// ---------------------------------------------------------------- flash attention, 1 wave per 16 q-rows
// qkv: bf16 [NTOK][3072], token row = b*S+s, q at col h*64+d, k at 1024+, v at 2048+
// out: x[token][E] += attn (cols h*64..h*64+63)
__global__ __launch_bounds__(64) void attn_kernel(const unsigned short* __restrict__ qkv,
                                                  float* __restrict__ x) {
    int qt = blockIdx.x, h = blockIdx.y, b = blockIdx.z;
    int lane = threadIdx.x;
    int l15 = lane & 15, g4 = lane >> 4;
    int s0 = qt * 16;
    const size_t base = (size_t)b * S * 3072;

    bf16x8 q[2];
    #pragma unroll
    for (int dc = 0; dc < 2; dc++)
        q[dc] = *(const bf16x8*)&qkv[base + (size_t)(s0 + l15) * 3072 + h * 64 + dc * 32 + 8 * g4];

    f32x4 O[4] = {};
    float m_run[4], l_run[4];
    #pragma unroll
    for (int j = 0; j < 4; j++) { m_run[j] = -INFINITY; l_run[j] = 0.0f; }

    __shared__ unsigned short P_lds[16][40];
    __shared__ unsigned short V_lds[64][40];

    int nkt = (s0 + 15) / 32;  // inclusive last tile index
    for (int kt = 0; kt <= nkt; kt++) {
        int k0 = kt * 32;
        // scores: S[16 q][32 keys] = Q @ K^T
        f32x4 sf[2];
        #pragma unroll
        for (int c = 0; c < 2; c++) {
            f32x4 z = {};
            bf16x8 kb0 = *(const bf16x8*)&qkv[base + (size_t)(k0 + c * 16 + l15) * 3072 + 1024 + h * 64 + 0 + 8 * g4];
            bf16x8 kb1 = *(const bf16x8*)&qkv[base + (size_t)(k0 + c * 16 + l15) * 3072 + 1024 + h * 64 + 32 + 8 * g4];
            z = __builtin_amdgcn_mfma_f32_16x16x32_bf16(q[0], kb0, z, 0, 0, 0);
            z = __builtin_amdgcn_mfma_f32_16x16x32_bf16(q[1], kb1, z, 0, 0, 0);
            sf[c] = z;
        }
        __syncthreads();  // prior-iter LDS reads done before overwrite
        // stage V tile transposed: V_lds[d][key]
        #pragma unroll
        for (int p = 0; p < 4; p++) {
            int idx = lane + p * 64;
            int key = idx >> 3, d8 = (idx & 7) * 8;
            uint4 v = *(const uint4*)&qkv[base + (size_t)(k0 + key) * 3072 + 2048 + h * 64 + d8];
            unsigned short* pv = (unsigned short*)&v;
            #pragma unroll
            for (int e = 0; e < 8; e++) V_lds[d8 + e][key] = pv[e];
        }
        // online softmax (f32)
        float pr[2][4];
        float alpha[4];
        #pragma unroll
        for (int j = 0; j < 4; j++) {
            int qrow = s0 + g4 * 4 + j;
            float v0 = sf[0][j] * 0.125f;
            float v1 = sf[1][j] * 0.125f;
            if (k0 + l15 > qrow) v0 = -INFINITY;
            if (k0 + 16 + l15 > qrow) v1 = -INFINITY;
            float tm = fmaxf(v0, v1);
            tm = fmaxf(tm, __shfl_xor(tm, 1, 16));
            tm = fmaxf(tm, __shfl_xor(tm, 2, 16));
            tm = fmaxf(tm, __shfl_xor(tm, 4, 16));
            tm = fmaxf(tm, __shfl_xor(tm, 8, 16));
            float mnew = fmaxf(m_run[j], tm);
            float p0 = __expf(v0 - mnew);
            float p1 = __expf(v1 - mnew);
            float ts = p0 + p1;
            ts += __shfl_xor(ts, 1, 16);
            ts += __shfl_xor(ts, 2, 16);
            ts += __shfl_xor(ts, 4, 16);
            ts += __shfl_xor(ts, 8, 16);
            alpha[j] = __expf(m_run[j] - mnew);
            l_run[j] = l_run[j] * alpha[j] + ts;
            m_run[j] = mnew;
            pr[0][j] = p0; pr[1][j] = p1;
        }
        #pragma unroll
        for (int f = 0; f < 4; f++)
            #pragma unroll
            for (int j = 0; j < 4; j++) O[f][j] *= alpha[j];
        // P -> LDS (bf16)
        #pragma unroll
        for (int c = 0; c < 2; c++)
            #pragma unroll
            for (int j = 0; j < 4; j++)
                P_lds[g4 * 4 + j][c * 16 + l15] = f2bf(pr[c][j]);
        __syncthreads();
        bf16x8 pa = *(const bf16x8*)&P_lds[l15][8 * g4];
        #pragma unroll
        for (int f = 0; f < 4; f++) {
            bf16x8 vb = *(const bf16x8*)&V_lds[f * 16 + l15][8 * g4];
            O[f] = __builtin_amdgcn_mfma_f32_16x16x32_bf16(pa, vb, O[f], 0, 0, 0);
        }
    }
    // write: x += O / l
    #pragma unroll
    for (int f = 0; f < 4; f++)
        #pragma unroll
        for (int j = 0; j < 4; j++) {
            size_t o = ((size_t)b * S + s0 + g4 * 4 + j) * E + h * 64 + f * 16 + l15;
            x[o] += O[f][j] / l_run[j];
        }
}

// ---------------------------------------------------------------- launch
extern "C" void kernel_launch(void* const* d_in, const int* in_sizes, int n_in,
                              void* d_out, int out_size, void* d_ws, size_t ws_size,
                              hipStream_t stream) {
    const int*   idx    = (const int*)d_in[0];
    const float* tok    = (const float*)d_in[1];
    const float* pos    = (const float*)d_in[2];
    const float* qkv_w  = (const float*)d_in[3];
    const float* qkv_b  = (const float*)d_in[4];
    const float* ln1_w  = (const float*)d_in[5];
    const float* ln1_b  = (const float*)d_in[6];
    const float* ln2_w  = (const float*)d_in[7];
    const float* ln2_b  = (const float*)d_in[8];
    const float* ff1_w  = (const float*)d_in[9];
    const float* ff1_b  = (const float*)d_in[10];
    const float* ff2_w  = (const float*)d_in[11];
    const float* ff2_b  = (const float*)d_in[12];
    const float* fin_w  = (const float*)d_in[13];
    const float* fin_b  = (const float*)d_in[14];
    const float* proj_w = (const float*)d_in[15];

    char* ws = (char*)d_ws;
    float*          x    = (float*)ws;                                   // 16 MB f32 residual
    unsigned short* xn   = (unsigned short*)(ws + 16777216);             // 8 MB bf16 LN out
    unsigned short* qkvb = (unsigned short*)(ws + 16777216 + 8388608);   // 24 MB bf16 qkv
    unsigned short* hbuf = (unsigned short*)(ws + 16777216 + 8388608 + 25165824);  // 32 MB bf16 ff hidden

    embed_kernel<<<NTOK, 256, 0, stream>>>(idx, tok, pos, x);
    for (int l = 0; l < DEPTH; l++) {
        ln_kernel<<<NTOK, 256, 0, stream>>>(x, ln1_w + l * E, ln1_b + l * E, xn);
        gemm_kernel<1, 0, 1, 0><<<dim3(24, 32), 256, 0, stream>>>(
            xn, qkv_w + (size_t)l * 3 * E * E, qkv_b + (size_t)l * 3 * E, nullptr, qkvb, NTOK, 3 * E, E);
        attn_kernel<<<dim3(S / 16, H, BB), 64, 0, stream>>>(qkvb, x);
        ln_kernel<<<NTOK, 256, 0, stream>>>(x, ln2_w + l * E, ln2_b + l * E, xn);
        gemm_kernel<1, 1, 1, 0><<<dim3(32, 32), 256, 0, stream>>>(
            xn, ff1_w + (size_t)l * 4 * E * E, ff1_b + (size_t)l * 4 * E, nullptr, hbuf, NTOK, 4 * E, E);
        gemm_kernel<0, 0, 1, 1><<<dim3(8, 32), 256, 0, stream>>>(
            hbuf, ff2_w + (size_t)l * E * 4 * E, ff2_b + (size_t)l * E, x, x, NTOK, E, 4 * E);
    }
    ln_kernel<<<NTOK, 256, 0, stream>>>(x, fin_w, fin_b, xn);
    gemm_kernel<0, 0, 0, 0><<<dim3(250, 32), 256, 0, stream>>>(
        xn, proj_w, nullptr, nullptr, d_out, NTOK, V, E);
}

// Round 2
// 4024.500 us; speedup vs baseline: 1.1709x; 1.1709x over previous
//
#include <hip/hip_runtime.h>
#include <hip/hip_bf16.h>

#define DEPTH 6
#define E 1024
#define H 16
#define S 2048
#define V 32000
#define BB 2
#define HD 64
#define NTOK (BB * S)  // 4096

typedef __attribute__((ext_vector_type(8))) short bf16x8;
typedef __attribute__((ext_vector_type(4))) float f32x4;
typedef unsigned short us;

__device__ inline us f2bf(float f) {
    union { float f; unsigned u; } v; v.f = f;
    unsigned r = v.u + 0x7fff + ((v.u >> 16) & 1);
    return (us)(r >> 16);
}

__device__ __forceinline__ void gld16(const us* g, us* l) {
    __builtin_amdgcn_global_load_lds(
        (const __attribute__((address_space(1))) unsigned int*)g,
        (__attribute__((address_space(3))) unsigned int*)l, 16, 0, 0);
}

// ---------------------------------------------------------------- f32 -> bf16 cast (8 elem/thread)
__global__ __launch_bounds__(256) void cast_kernel(const float* __restrict__ in,
                                                   us* __restrict__ out, int n8) {
    int i = blockIdx.x * 256 + threadIdx.x;
    if (i >= n8) return;
    const float4* p = (const float4*)in + 2 * (size_t)i;
    float4 a = p[0], b = p[1];
    uint4 o;
    o.x = f2bf(a.x) | ((unsigned)f2bf(a.y) << 16);
    o.y = f2bf(a.z) | ((unsigned)f2bf(a.w) << 16);
    o.z = f2bf(b.x) | ((unsigned)f2bf(b.y) << 16);
    o.w = f2bf(b.z) | ((unsigned)f2bf(b.w) << 16);
    ((uint4*)out)[i] = o;
}

// ---------------------------------------------------------------- embedding
__global__ void embed_kernel(const int* __restrict__ idx, const float* __restrict__ tok,
                             const float* __restrict__ pos, float* __restrict__ x) {
    int t = blockIdx.x;
    int s = t & (S - 1);
    int tokid = idx[t];
    int c = threadIdx.x * 4;
    float4 a = *(const float4*)&tok[(size_t)tokid * E + c];
    float4 p = *(const float4*)&pos[(size_t)s * E + c];
    float4 o; o.x = a.x + p.x; o.y = a.y + p.y; o.z = a.z + p.z; o.w = a.w + p.w;
    *(float4*)&x[(size_t)t * E + c] = o;
}

// ---------------------------------------------------------------- layernorm (f32 in, bf16 out)
__global__ __launch_bounds__(256) void ln_kernel(const float* __restrict__ x,
                                                 const float* __restrict__ w,
                                                 const float* __restrict__ b,
                                                 us* __restrict__ out) {
    int row = blockIdx.x;
    int tid = threadIdx.x;
    int c = tid * 4;
    float4 v = *(const float4*)&x[(size_t)row * E + c];
    float s  = v.x + v.y + v.z + v.w;
    float sq = v.x * v.x + v.y * v.y + v.z * v.z + v.w * v.w;
    __shared__ float red[8];
    for (int o = 32; o > 0; o >>= 1) { s += __shfl_xor(s, o); sq += __shfl_xor(sq, o); }
    int wave = tid >> 6, lane = tid & 63;
    if (lane == 0) { red[wave] = s; red[4 + wave] = sq; }
    __syncthreads();
    if (tid == 0) {
        red[0] = red[0] + red[1] + red[2] + red[3];
        red[4] = red[4] + red[5] + red[6] + red[7];
    }
    __syncthreads();
    float mean = red[0] * (1.0f / E);
    float var  = red[4] * (1.0f / E) - mean * mean;
    float rstd = rsqrtf(var + 1e-5f);
    float4 wv = *(const float4*)&w[c];
    float4 bv = *(const float4*)&b[c];
    unsigned a0 = f2bf((v.x - mean) * rstd * wv.x + bv.x);
    unsigned a1 = f2bf((v.y - mean) * rstd * wv.y + bv.y);
    unsigned a2 = f2bf((v.z - mean) * rstd * wv.z + bv.z);
    unsigned a3 = f2bf((v.w - mean) * rstd * wv.w + bv.w);
    uint2 o; o.x = a0 | (a1 << 16); o.y = a2 | (a3 << 16);
    *(uint2*)&out[(size_t)row * E + c] = o;
}

// ---------------------------------------------------------------- GEMM m97-structure
// C[M][ldo] = A(bf16 [M][K]) * Bw(bf16 [N][K])^T, 128x128 tile, BK=32, 4 waves,
// global_load_lds width-16 staging, XCD-bijective swizzle, M-fastest ordering.
template <int OUT_BF16, int ACT_GELU, int HAS_BIAS, int HAS_RES>
__global__ __launch_bounds__(256) void gemm_bf16(const us* __restrict__ A,
                                                 const us* __restrict__ Bw,
                                                 const float* __restrict__ bias,
                                                 const float* __restrict__ res,
                                                 void* __restrict__ outp,
                                                 int M, int N, int K, int ldo) {
    __shared__ us As[128 * 32];
    __shared__ us Bs[128 * 32];
    int tid = threadIdx.x;
    int nwg = gridDim.x;
    int chunk = nwg >> 3;                       // nwg % 8 == 0 guaranteed by launch
    int wgid = blockIdx.x;
    int sw = (wgid & 7) * chunk + (wgid >> 3);  // bijective XCD swizzle
    int MB = M >> 7;
    int bm = (sw % MB) * 128;                   // M-fastest: consecutive sw share B-panel
    int bn = (sw / MB) * 128;

    int wave = tid >> 6, lane = tid & 63;
    int wr = wave >> 1, wc = wave & 1;
    int l15 = lane & 15, g4 = lane >> 4;
    f32x4 acc[4][4] = {};

    for (int k0 = 0; k0 < K; k0 += 32) {
        #pragma unroll
        for (int p = 0; p < 2; p++) {
            int e = tid + p * 256;              // element-octet index 0..511
            int row = e >> 2, col8 = (e & 3) * 8;
            gld16(&A[(size_t)(bm + row) * K + k0 + col8], &As[e * 8]);
            gld16(&Bw[(size_t)(bn + row) * K + k0 + col8], &Bs[e * 8]);
        }
        __syncthreads();   // compiler emits vmcnt(0) drain before barrier
        bf16x8 a[4], bfr[4];
        #pragma unroll
        for (int m = 0; m < 4; m++) a[m] = *(const bf16x8*)&As[(wr * 64 + m * 16 + l15) * 32 + g4 * 8];
        #pragma unroll
        for (int n = 0; n < 4; n++) bfr[n] = *(const bf16x8*)&Bs[(wc * 64 + n * 16 + l15) * 32 + g4 * 8];
        #pragma unroll
        for (int m = 0; m < 4; m++)
            #pragma unroll
            for (int n = 0; n < 4; n++)
                acc[m][n] = __builtin_amdgcn_mfma_f32_16x16x32_bf16(a[m], bfr[n], acc[m][n], 0, 0, 0);
        __syncthreads();
    }

    float* outf = (float*)outp;
    us* outb = (us*)outp;
    #pragma unroll
    for (int m = 0; m < 4; m++)
        #pragma unroll
        for (int n = 0; n < 4; n++)
            #pragma unroll
            for (int j = 0; j < 4; j++) {
                int r = bm + wr * 64 + m * 16 + g4 * 4 + j;
                int c = bn + wc * 64 + n * 16 + l15;
                float v = acc[m][n][j];
                if (HAS_BIAS) v += bias[c];
                if (ACT_GELU) v = 0.5f * v * (1.0f + erff(v * 0.70710678118f));
                if (HAS_RES) v += res[(size_t)r * ldo + c];
                if (OUT_BF16) outb[(size_t)r * ldo + c] = f2bf(v);
                else outf[(size_t)r * ldo + c] = v;
            }
}

// ---------------------------------------------------------------- flash attention, 1 wave per 16 q-rows
__global__ __launch_bounds__(64) void attn_kernel(const us* __restrict__ qkv,
                                                  float* __restrict__ x) {
    int qt = blockIdx.x, h = blockIdx.y, b = blockIdx.z;
    int lane = threadIdx.x;
    int l15 = lane & 15, g4 = lane >> 4;
    int s0 = qt * 16;
    const size_t base = (size_t)b * S * 3072;

    bf16x8 q[2];
    #pragma unroll
    for (int dc = 0; dc < 2; dc++)
        q[dc] = *(const bf16x8*)&qkv[base + (size_t)(s0 + l15) * 3072 + h * 64 + dc * 32 + 8 * g4];

    f32x4 O[4] = {};
    float m_run[4], l_run[4];
    #pragma unroll
    for (int j = 0; j < 4; j++) { m_run[j] = -INFINITY; l_run[j] = 0.0f; }

    __shared__ us P_lds[16][40];
    __shared__ us V_lds[64][40];

    int nkt = (s0 + 15) / 32;
    for (int kt = 0; kt <= nkt; kt++) {
        int k0 = kt * 32;
        f32x4 sf[2];
        #pragma unroll
        for (int c = 0; c < 2; c++) {
            f32x4 z = {};
            bf16x8 kb0 = *(const bf16x8*)&qkv[base + (size_t)(k0 + c * 16 + l15) * 3072 + 1024 + h * 64 + 0 + 8 * g4];
            bf16x8 kb1 = *(const bf16x8*)&qkv[base + (size_t)(k0 + c * 16 + l15) * 3072 + 1024 + h * 64 + 32 + 8 * g4];
            z = __builtin_amdgcn_mfma_f32_16x16x32_bf16(q[0], kb0, z, 0, 0, 0);
            z = __builtin_amdgcn_mfma_f32_16x16x32_bf16(q[1], kb1, z, 0, 0, 0);
            sf[c] = z;
        }
        __syncthreads();
        #pragma unroll
        for (int p = 0; p < 4; p++) {
            int idx = lane + p * 64;
            int key = idx >> 3, d8 = (idx & 7) * 8;
            uint4 v = *(const uint4*)&qkv[base + (size_t)(k0 + key) * 3072 + 2048 + h * 64 + d8];
            us* pv = (us*)&v;
            #pragma unroll
            for (int e = 0; e < 8; e++) V_lds[d8 + e][key] = pv[e];
        }
        float pr[2][4];
        float alpha[4];
        #pragma unroll
        for (int j = 0; j < 4; j++) {
            int qrow = s0 + g4 * 4 + j;
            float v0 = sf[0][j] * 0.125f;
            float v1 = sf[1][j] * 0.125f;
            if (k0 + l15 > qrow) v0 = -INFINITY;
            if (k0 + 16 + l15 > qrow) v1 = -INFINITY;
            float tm = fmaxf(v0, v1);
            tm = fmaxf(tm, __shfl_xor(tm, 1, 16));
            tm = fmaxf(tm, __shfl_xor(tm, 2, 16));
            tm = fmaxf(tm, __shfl_xor(tm, 4, 16));
            tm = fmaxf(tm, __shfl_xor(tm, 8, 16));
            float mnew = fmaxf(m_run[j], tm);
            float p0 = __expf(v0 - mnew);
            float p1 = __expf(v1 - mnew);
            float ts = p0 + p1;
            ts += __shfl_xor(ts, 1, 16);
            ts += __shfl_xor(ts, 2, 16);
            ts += __shfl_xor(ts, 4, 16);
            ts += __shfl_xor(ts, 8, 16);
            alpha[j] = __expf(m_run[j] - mnew);
            l_run[j] = l_run[j] * alpha[j] + ts;
            m_run[j] = mnew;
            pr[0][j] = p0; pr[1][j] = p1;
        }
        #pragma unroll
        for (int f = 0; f < 4; f++)
            #pragma unroll
            for (int j = 0; j < 4; j++) O[f][j] *= alpha[j];
        #pragma unroll
        for (int c = 0; c < 2; c++)
            #pragma unroll
            for (int j = 0; j < 4; j++)
                P_lds[g4 * 4 + j][c * 16 + l15] = f2bf(pr[c][j]);
        __syncthreads();
        bf16x8 pa = *(const bf16x8*)&P_lds[l15][8 * g4];
        #pragma unroll
        for (int f = 0; f < 4; f++) {
            bf16x8 vb = *(const bf16x8*)&V_lds[f * 16 + l15][8 * g4];
            O[f] = __builtin_amdgcn_mfma_f32_16x16x32_bf16(pa, vb, O[f], 0, 0, 0);
        }
    }
    #pragma unroll
    for (int f = 0; f < 4; f++)
        #pragma unroll
        for (int j = 0; j < 4; j++) {
            size_t o = ((size_t)b * S + s0 + g4 * 4 + j) * E + h * 64 + f * 16 + l15;
            x[o] += O[f][j] / l_run[j];
        }
}

// ---------------------------------------------------------------- launch
extern "C" void kernel_launch(void* const* d_in, const int* in_sizes, int n_in,
                              void* d_out, int out_size, void* d_ws, size_t ws_size,
                              hipStream_t stream) {
    const int*   idx    = (const int*)d_in[0];
    const float* tok    = (const float*)d_in[1];
    const float* pos    = (const float*)d_in[2];
    const float* qkv_w  = (const float*)d_in[3];
    const float* qkv_b  = (const float*)d_in[4];
    const float* ln1_w  = (const float*)d_in[5];
    const float* ln1_b  = (const float*)d_in[6];
    const float* ln2_w  = (const float*)d_in[7];
    const float* ln2_b  = (const float*)d_in[8];
    const float* ff1_w  = (const float*)d_in[9];
    const float* ff1_b  = (const float*)d_in[10];
    const float* ff2_w  = (const float*)d_in[11];
    const float* ff2_b  = (const float*)d_in[12];
    const float* fin_w  = (const float*)d_in[13];
    const float* fin_b  = (const float*)d_in[14];
    const float* proj_w = (const float*)d_in[15];

    char* ws = (char*)d_ws;
    float* x    = (float*)ws;                          // 16.78 MB f32 residual
    us*    xn   = (us*)(ws + 16777216);                // 8.39 MB bf16 LN out
    us*    qkvb = (us*)(ws + 25165824);                // 25.17 MB bf16 qkv
    us*    hbuf = (us*)(ws + 50331648);                // 33.55 MB bf16 ff hidden
    us*    wbuf = (us*)(ws + 83886080);                // 8.39 MB bf16 per-layer weights
    us*    pbuf = qkvb;                                // 32.77 MB proj weight half (qkvb+hbuf free then)

    embed_kernel<<<NTOK, 256, 0, stream>>>(idx, tok, pos, x);
    for (int l = 0; l < DEPTH; l++) {
        ln_kernel<<<NTOK, 256, 0, stream>>>(x, ln1_w + l * E, ln1_b + l * E, xn);
        cast_kernel<<<1536, 256, 0, stream>>>(qkv_w + (size_t)l * 3 * E * E, wbuf, 3 * E * E / 8);
        gemm_bf16<1, 0, 1, 0><<<768, 256, 0, stream>>>(
            xn, wbuf, qkv_b + l * 3 * E, nullptr, qkvb, NTOK, 3 * E, E, 3 * E);
        attn_kernel<<<dim3(S / 16, H, BB), 64, 0, stream>>>(qkvb, x);
        ln_kernel<<<NTOK, 256, 0, stream>>>(x, ln2_w + l * E, ln2_b + l * E, xn);
        cast_kernel<<<2048, 256, 0, stream>>>(ff1_w + (size_t)l * 4 * E * E, wbuf, 4 * E * E / 8);
        gemm_bf16<1, 1, 1, 0><<<1024, 256, 0, stream>>>(
            xn, wbuf, ff1_b + l * 4 * E, nullptr, hbuf, NTOK, 4 * E, E, 4 * E);
        cast_kernel<<<2048, 256, 0, stream>>>(ff2_w + (size_t)l * E * 4 * E, wbuf, 4 * E * E / 8);
        gemm_bf16<0, 0, 1, 1><<<256, 256, 0, stream>>>(
            hbuf, wbuf, ff2_b + l * E, x, x, NTOK, E, 4 * E, E);
    }
    ln_kernel<<<NTOK, 256, 0, stream>>>(x, fin_w, fin_b, xn);
    for (int hf = 0; hf < 2; hf++) {
        cast_kernel<<<8000, 256, 0, stream>>>(proj_w + (size_t)hf * 16000 * E, pbuf, 16000 * E / 8);
        gemm_bf16<0, 0, 0, 0><<<4000, 256, 0, stream>>>(
            xn, pbuf, nullptr, nullptr, (float*)d_out + hf * 16000, NTOK, 16000, E, V);
    }
}

// Round 3
// 2503.624 us; speedup vs baseline: 1.8823x; 1.6075x over previous
//
#include <hip/hip_runtime.h>
#include <hip/hip_bf16.h>

#define DEPTH 6
#define E 1024
#define H 16
#define S 2048
#define V 32000
#define BB 2
#define HD 64
#define NTOK (BB * S)  // 4096

typedef __attribute__((ext_vector_type(8))) short bf16x8;
typedef __attribute__((ext_vector_type(4))) float f32x4;
typedef unsigned short us;

__device__ inline us f2bf(float f) {
    union { float f; unsigned u; } v; v.f = f;
    unsigned r = v.u + 0x7fff + ((v.u >> 16) & 1);
    return (us)(r >> 16);
}

__device__ __forceinline__ void gld16(const us* g, us* l) {
    __builtin_amdgcn_global_load_lds(
        (const __attribute__((address_space(1))) unsigned int*)g,
        (__attribute__((address_space(3))) unsigned int*)l, 16, 0, 0);
}

// ---------------------------------------------------------------- f32 -> bf16 cast
__global__ __launch_bounds__(256) void cast_kernel(const float* __restrict__ in,
                                                   us* __restrict__ out, int n8) {
    int i = blockIdx.x * 256 + threadIdx.x;
    if (i >= n8) return;
    const float4* p = (const float4*)in + 2 * (size_t)i;
    float4 a = p[0], b = p[1];
    uint4 o;
    o.x = f2bf(a.x) | ((unsigned)f2bf(a.y) << 16);
    o.y = f2bf(a.z) | ((unsigned)f2bf(a.w) << 16);
    o.z = f2bf(b.x) | ((unsigned)f2bf(b.y) << 16);
    o.w = f2bf(b.z) | ((unsigned)f2bf(b.w) << 16);
    ((uint4*)out)[i] = o;
}

// ---------------------------------------------------------------- embedding
__global__ void embed_kernel(const int* __restrict__ idx, const float* __restrict__ tok,
                             const float* __restrict__ pos, float* __restrict__ x) {
    int t = blockIdx.x;
    int s = t & (S - 1);
    int tokid = idx[t];
    int c = threadIdx.x * 4;
    float4 a = *(const float4*)&tok[(size_t)tokid * E + c];
    float4 p = *(const float4*)&pos[(size_t)s * E + c];
    float4 o; o.x = a.x + p.x; o.y = a.y + p.y; o.z = a.z + p.z; o.w = a.w + p.w;
    *(float4*)&x[(size_t)t * E + c] = o;
}

// ---------------------------------------------------------------- layernorm
__global__ __launch_bounds__(256) void ln_kernel(const float* __restrict__ x,
                                                 const float* __restrict__ w,
                                                 const float* __restrict__ b,
                                                 us* __restrict__ out) {
    int row = blockIdx.x;
    int tid = threadIdx.x;
    int c = tid * 4;
    float4 v = *(const float4*)&x[(size_t)row * E + c];
    float s  = v.x + v.y + v.z + v.w;
    float sq = v.x * v.x + v.y * v.y + v.z * v.z + v.w * v.w;
    __shared__ float red[8];
    for (int o = 32; o > 0; o >>= 1) { s += __shfl_xor(s, o); sq += __shfl_xor(sq, o); }
    int wave = tid >> 6, lane = tid & 63;
    if (lane == 0) { red[wave] = s; red[4 + wave] = sq; }
    __syncthreads();
    if (tid == 0) {
        red[0] = red[0] + red[1] + red[2] + red[3];
        red[4] = red[4] + red[5] + red[6] + red[7];
    }
    __syncthreads();
    float mean = red[0] * (1.0f / E);
    float var  = red[4] * (1.0f / E) - mean * mean;
    float rstd = rsqrtf(var + 1e-5f);
    float4 wv = *(const float4*)&w[c];
    float4 bv = *(const float4*)&b[c];
    unsigned a0 = f2bf((v.x - mean) * rstd * wv.x + bv.x);
    unsigned a1 = f2bf((v.y - mean) * rstd * wv.y + bv.y);
    unsigned a2 = f2bf((v.z - mean) * rstd * wv.z + bv.z);
    unsigned a3 = f2bf((v.w - mean) * rstd * wv.w + bv.w);
    uint2 o; o.x = a0 | (a1 << 16); o.y = a2 | (a3 << 16);
    *(uint2*)&out[(size_t)row * E + c] = o;
}

// ---------------------------------------------------------------- GEMM m97-structure
template <int OUT_BF16, int ACT_GELU, int HAS_BIAS, int HAS_RES>
__global__ __launch_bounds__(256) void gemm_bf16(const us* __restrict__ A,
                                                 const us* __restrict__ Bw,
                                                 const float* __restrict__ bias,
                                                 const float* __restrict__ res,
                                                 void* __restrict__ outp,
                                                 int M, int N, int K, int ldo) {
    __shared__ us As[128 * 32];
    __shared__ us Bs[128 * 32];
    int tid = threadIdx.x;
    int nwg = gridDim.x;
    int chunk = nwg >> 3;
    int wgid = blockIdx.x;
    int sw = (wgid & 7) * chunk + (wgid >> 3);
    int MB = M >> 7;
    int bm = (sw % MB) * 128;
    int bn = (sw / MB) * 128;

    int wave = tid >> 6, lane = tid & 63;
    int wr = wave >> 1, wc = wave & 1;
    int l15 = lane & 15, g4 = lane >> 4;
    f32x4 acc[4][4] = {};

    for (int k0 = 0; k0 < K; k0 += 32) {
        #pragma unroll
        for (int p = 0; p < 2; p++) {
            int e = tid + p * 256;
            int row = e >> 2, col8 = (e & 3) * 8;
            gld16(&A[(size_t)(bm + row) * K + k0 + col8], &As[e * 8]);
            gld16(&Bw[(size_t)(bn + row) * K + k0 + col8], &Bs[e * 8]);
        }
        __syncthreads();
        bf16x8 a[4], bfr[4];
        #pragma unroll
        for (int m = 0; m < 4; m++) a[m] = *(const bf16x8*)&As[(wr * 64 + m * 16 + l15) * 32 + g4 * 8];
        #pragma unroll
        for (int n = 0; n < 4; n++) bfr[n] = *(const bf16x8*)&Bs[(wc * 64 + n * 16 + l15) * 32 + g4 * 8];
        #pragma unroll
        for (int m = 0; m < 4; m++)
            #pragma unroll
            for (int n = 0; n < 4; n++)
                acc[m][n] = __builtin_amdgcn_mfma_f32_16x16x32_bf16(a[m], bfr[n], acc[m][n], 0, 0, 0);
        __syncthreads();
    }

    float* outf = (float*)outp;
    us* outb = (us*)outp;
    #pragma unroll
    for (int m = 0; m < 4; m++)
        #pragma unroll
        for (int n = 0; n < 4; n++)
            #pragma unroll
            for (int j = 0; j < 4; j++) {
                int r = bm + wr * 64 + m * 16 + g4 * 4 + j;
                int c = bn + wc * 64 + n * 16 + l15;
                float v = acc[m][n][j];
                if (HAS_BIAS) v += bias[c];
                if (ACT_GELU) v = 0.5f * v * (1.0f + erff(v * 0.70710678118f));
                if (HAS_RES) v += res[(size_t)r * ldo + c];
                if (OUT_BF16) outb[(size_t)r * ldo + c] = f2bf(v);
                else outf[(size_t)r * ldo + c] = v;
            }
}

// ---------------------------------------------------------------- V transpose: qkv[tok][2048+h*64+d] -> vT[b][h][d][s]
__global__ __launch_bounds__(256) void transpose_v(const us* __restrict__ qkv,
                                                   us* __restrict__ vT) {
    int kt = blockIdx.x, h = blockIdx.y, b = blockIdx.z;
    int tid = threadIdx.x;
    __shared__ us T[64][72];   // 144B row stride: 16B-aligned, conflict-free both phases
    const size_t base = (size_t)b * S * 3072 + 2048 + h * 64;
    int k0 = kt * 64;
    #pragma unroll
    for (int it = 0; it < 2; it++) {
        int p = tid + it * 256;
        int key = p & 63, c8 = (p >> 6) * 8;   // scattered keys: L1 absorbs (rows reused 8x)
        uint4 v = *(const uint4*)&qkv[base + (size_t)(k0 + key) * 3072 + c8];
        us* pv = (us*)&v;
        #pragma unroll
        for (int e = 0; e < 8; e++) T[c8 + e][key] = pv[e];
    }
    __syncthreads();
    const size_t obase = ((size_t)(b * H + h) * 64) * S + k0;
    #pragma unroll
    for (int it = 0; it < 2; it++) {
        int o = tid + it * 256;
        int d = o >> 3, cc = (o & 7) * 8;
        uint4 v = *(const uint4*)&T[d][cc];
        *(uint4*)&vT[obase + (size_t)d * S + cc] = v;   // 8 lanes/row -> 128B coalesced
    }
}

// ---------------------------------------------------------------- flash attention: 8 waves, QBLK=128, KVB=64
// K_lds/VT_lds: linear gld16 dest + inverse-swizzled source + swizzled read (rule #21)
__global__ __launch_bounds__(512, 4) void attn_kernel(const us* __restrict__ qkv,
                                                      const us* __restrict__ vT,
                                                      float* __restrict__ x) {
    int qt = blockIdx.x, h = blockIdx.y, b = blockIdx.z;
    int tid = threadIdx.x;
    int w = tid >> 6, lane = tid & 63;
    int l15 = lane & 15, g4 = lane >> 4;
    int s0 = qt * 128;
    int qrow_base = s0 + w * 16;
    const size_t qbase = (size_t)b * S * 3072;
    const size_t vtbase = ((size_t)(b * H + h) * 64) * S;

    __shared__ us K_lds[2][64 * 64];
    __shared__ us VT_lds[2][64 * 64];
    __shared__ us P_lds[8][16 * 72];

    bf16x8 q[2];
    #pragma unroll
    for (int dc = 0; dc < 2; dc++)
        q[dc] = *(const bf16x8*)&qkv[qbase + (size_t)(qrow_base + l15) * 3072 + h * 64 + dc * 32 + 8 * g4];

    f32x4 O[4] = {};
    float m_run[4], l_run[4];
    #pragma unroll
    for (int j = 0; j < 4; j++) { m_run[j] = -INFINITY; l_run[j] = 0.0f; }

    int lastt = 2 * qt + 1;
    // stage tile 0
    {
        int p = tid, row = p >> 3, cc = p & 7;
        int scc = cc ^ (row & 7);
        gld16(&qkv[qbase + (size_t)(0 + row) * 3072 + 1024 + h * 64 + scc * 8], &K_lds[0][p * 8]);
        gld16(&vT[vtbase + (size_t)row * S + 0 + scc * 8], &VT_lds[0][p * 8]);
    }
    __syncthreads();

    for (int t = 0; t <= lastt; t++) {
        int bb = t & 1;
        if (t < lastt) {   // prefetch next tile into other buffer (2-phase)
            int p = tid, row = p >> 3, cc = p & 7;
            int scc = cc ^ (row & 7);
            gld16(&qkv[qbase + (size_t)((t + 1) * 64 + row) * 3072 + 1024 + h * 64 + scc * 8], &K_lds[bb ^ 1][p * 8]);
            gld16(&vT[vtbase + (size_t)row * S + (t + 1) * 64 + scc * 8], &VT_lds[bb ^ 1][p * 8]);
        }
        int k0 = t * 64;
        if (k0 <= qrow_base + 15) {   // wave-uniform causal skip
            // ---- QK^T: S[16q][64k]
            f32x4 sf[4];
            #pragma unroll
            for (int c = 0; c < 4; c++) {
                f32x4 z = {};
                int row = c * 16 + l15;
                #pragma unroll
                for (int dc = 0; dc < 2; dc++) {
                    int ch = (dc * 4 + g4) ^ (row & 7);
                    bf16x8 kb = *(const bf16x8*)&K_lds[bb][row * 64 + ch * 8];
                    z = __builtin_amdgcn_mfma_f32_16x16x32_bf16(q[dc], kb, z, 0, 0, 0);
                }
                sf[c] = z;
            }
            // ---- online softmax
            bool needmask = (k0 + 63 > qrow_base);
            float pr[4][4], alpha[4];
            #pragma unroll
            for (int j = 0; j < 4; j++) {
                int qrow = qrow_base + g4 * 4 + j;
                float v0 = sf[0][j] * 0.125f, v1 = sf[1][j] * 0.125f;
                float v2 = sf[2][j] * 0.125f, v3 = sf[3][j] * 0.125f;
                if (needmask) {
                    if (k0 +      l15 > qrow) v0 = -INFINITY;
                    if (k0 + 16 + l15 > qrow) v1 = -INFINITY;
                    if (k0 + 32 + l15 > qrow) v2 = -INFINITY;
                    if (k0 + 48 + l15 > qrow) v3 = -INFINITY;
                }
                float tm = fmaxf(fmaxf(v0, v1), fmaxf(v2, v3));
                tm = fmaxf(tm, __shfl_xor(tm, 1, 16));
                tm = fmaxf(tm, __shfl_xor(tm, 2, 16));
                tm = fmaxf(tm, __shfl_xor(tm, 4, 16));
                tm = fmaxf(tm, __shfl_xor(tm, 8, 16));
                float mnew = fmaxf(m_run[j], tm);
                float p0 = __expf(v0 - mnew), p1 = __expf(v1 - mnew);
                float p2 = __expf(v2 - mnew), p3 = __expf(v3 - mnew);
                float ts = (p0 + p1) + (p2 + p3);
                ts += __shfl_xor(ts, 1, 16);
                ts += __shfl_xor(ts, 2, 16);
                ts += __shfl_xor(ts, 4, 16);
                ts += __shfl_xor(ts, 8, 16);
                alpha[j] = __expf(m_run[j] - mnew);
                l_run[j] = l_run[j] * alpha[j] + ts;
                m_run[j] = mnew;
                pr[0][j] = p0; pr[1][j] = p1; pr[2][j] = p2; pr[3][j] = p3;
            }
            #pragma unroll
            for (int f = 0; f < 4; f++)
                #pragma unroll
                for (int j = 0; j < 4; j++) O[f][j] *= alpha[j];
            // ---- P -> LDS (wave-private, no barrier)
            us* Pw = &P_lds[w][0];
            #pragma unroll
            for (int c = 0; c < 4; c++)
                #pragma unroll
                for (int j = 0; j < 4; j++)
                    Pw[(g4 * 4 + j) * 72 + c * 16 + l15] = f2bf(pr[c][j]);
            // ---- PV
            #pragma unroll
            for (int kc = 0; kc < 2; kc++) {
                bf16x8 pa = *(const bf16x8*)&Pw[l15 * 72 + kc * 32 + g4 * 8];
                #pragma unroll
                for (int dt = 0; dt < 4; dt++) {
                    int row = dt * 16 + l15;
                    int ch = (kc * 4 + g4) ^ (row & 7);
                    bf16x8 vb = *(const bf16x8*)&VT_lds[bb][row * 64 + ch * 8];
                    O[dt] = __builtin_amdgcn_mfma_f32_16x16x32_bf16(pa, vb, O[dt], 0, 0, 0);
                }
            }
        }
        __syncthreads();   // drains prefetch vmcnt + releases buffers
    }
    #pragma unroll
    for (int dt = 0; dt < 4; dt++)
        #pragma unroll
        for (int j = 0; j < 4; j++) {
            size_t o = ((size_t)b * S + qrow_base + g4 * 4 + j) * E + h * 64 + dt * 16 + l15;
            x[o] += O[dt][j] / l_run[j];
        }
}

// ---------------------------------------------------------------- launch
extern "C" void kernel_launch(void* const* d_in, const int* in_sizes, int n_in,
                              void* d_out, int out_size, void* d_ws, size_t ws_size,
                              hipStream_t stream) {
    const int*   idx    = (const int*)d_in[0];
    const float* tok    = (const float*)d_in[1];
    const float* pos    = (const float*)d_in[2];
    const float* qkv_w  = (const float*)d_in[3];
    const float* qkv_b  = (const float*)d_in[4];
    const float* ln1_w  = (const float*)d_in[5];
    const float* ln1_b  = (const float*)d_in[6];
    const float* ln2_w  = (const float*)d_in[7];
    const float* ln2_b  = (const float*)d_in[8];
    const float* ff1_w  = (const float*)d_in[9];
    const float* ff1_b  = (const float*)d_in[10];
    const float* ff2_w  = (const float*)d_in[11];
    const float* ff2_b  = (const float*)d_in[12];
    const float* fin_w  = (const float*)d_in[13];
    const float* fin_b  = (const float*)d_in[14];
    const float* proj_w = (const float*)d_in[15];

    char* ws = (char*)d_ws;
    float* x    = (float*)ws;                          // 16.78 MB f32 residual
    us*    xn   = (us*)(ws + 16777216);                // 8.39 MB bf16 LN out
    us*    qkvb = (us*)(ws + 25165824);                // 25.17 MB bf16 qkv
    us*    hbuf = (us*)(ws + 50331648);                // 33.55 MB bf16 ff hidden
    us*    wbuf = (us*)(ws + 83886080);                // 8.39 MB bf16 per-layer weights
    us*    vTb  = (us*)(ws + 92274688);                // 8.39 MB bf16 V^T [b][h][d][s]
    us*    pbuf = qkvb;                                // proj weight half reuses qkvb+hbuf space

    embed_kernel<<<NTOK, 256, 0, stream>>>(idx, tok, pos, x);
    for (int l = 0; l < DEPTH; l++) {
        ln_kernel<<<NTOK, 256, 0, stream>>>(x, ln1_w + l * E, ln1_b + l * E, xn);
        cast_kernel<<<1536, 256, 0, stream>>>(qkv_w + (size_t)l * 3 * E * E, wbuf, 3 * E * E / 8);
        gemm_bf16<1, 0, 1, 0><<<768, 256, 0, stream>>>(
            xn, wbuf, qkv_b + l * 3 * E, nullptr, qkvb, NTOK, 3 * E, E, 3 * E);
        transpose_v<<<dim3(S / 64, H, BB), 256, 0, stream>>>(qkvb, vTb);
        attn_kernel<<<dim3(S / 128, H, BB), 512, 0, stream>>>(qkvb, vTb, x);
        ln_kernel<<<NTOK, 256, 0, stream>>>(x, ln2_w + l * E, ln2_b + l * E, xn);
        cast_kernel<<<2048, 256, 0, stream>>>(ff1_w + (size_t)l * 4 * E * E, wbuf, 4 * E * E / 8);
        gemm_bf16<1, 1, 1, 0><<<1024, 256, 0, stream>>>(
            xn, wbuf, ff1_b + l * 4 * E, nullptr, hbuf, NTOK, 4 * E, E, 4 * E);
        cast_kernel<<<2048, 256, 0, stream>>>(ff2_w + (size_t)l * E * 4 * E, wbuf, 4 * E * E / 8);
        gemm_bf16<0, 0, 1, 1><<<256, 256, 0, stream>>>(
            hbuf, wbuf, ff2_b + l * E, x, x, NTOK, E, 4 * E, E);
    }
    ln_kernel<<<NTOK, 256, 0, stream>>>(x, fin_w, fin_b, xn);
    for (int hf = 0; hf < 2; hf++) {
        cast_kernel<<<8000, 256, 0, stream>>>(proj_w + (size_t)hf * 16000 * E, pbuf, 16000 * E / 8);
        gemm_bf16<0, 0, 0, 0><<<4000, 256, 0, stream>>>(
            xn, pbuf, nullptr, nullptr, (float*)d_out + hf * 16000, NTOK, 16000, E, V);
    }
}

// Round 4
// 2190.696 us; speedup vs baseline: 2.1511x; 1.1428x over previous
//
#include <hip/hip_runtime.h>
#include <hip/hip_bf16.h>

#define DEPTH 6
#define E 1024
#define H 16
#define S 2048
#define V 32000
#define BB 2
#define HD 64
#define NTOK (BB * S)  // 4096

typedef __attribute__((ext_vector_type(8))) short bf16x8;
typedef __attribute__((ext_vector_type(4))) float f32x4;
typedef unsigned short us;

__device__ inline us f2bf(float f) {
    union { float f; unsigned u; } v; v.f = f;
    unsigned r = v.u + 0x7fff + ((v.u >> 16) & 1);
    return (us)(r >> 16);
}
__device__ inline float bf2f(us b) {
    union { unsigned u; float f; } v; v.u = ((unsigned)b) << 16;
    return v.f;
}

__device__ __forceinline__ void gld16(const us* g, us* l) {
    __builtin_amdgcn_global_load_lds(
        (const __attribute__((address_space(1))) unsigned int*)g,
        (__attribute__((address_space(3))) unsigned int*)l, 16, 0, 0);
}

// ---------------------------------------------------------------- f32 -> bf16 cast
__global__ __launch_bounds__(256) void cast_kernel(const float* __restrict__ in,
                                                   us* __restrict__ out, int n8) {
    int i = blockIdx.x * 256 + threadIdx.x;
    if (i >= n8) return;
    const float4* p = (const float4*)in + 2 * (size_t)i;
    float4 a = p[0], b = p[1];
    uint4 o;
    o.x = f2bf(a.x) | ((unsigned)f2bf(a.y) << 16);
    o.y = f2bf(a.z) | ((unsigned)f2bf(a.w) << 16);
    o.z = f2bf(b.x) | ((unsigned)f2bf(b.y) << 16);
    o.w = f2bf(b.z) | ((unsigned)f2bf(b.w) << 16);
    ((uint4*)out)[i] = o;
}

// ---------------------------------------------------------------- embedding
__global__ void embed_kernel(const int* __restrict__ idx, const float* __restrict__ tok,
                             const float* __restrict__ pos, float* __restrict__ x) {
    int t = blockIdx.x;
    int s = t & (S - 1);
    int tokid = idx[t];
    int c = threadIdx.x * 4;
    float4 a = *(const float4*)&tok[(size_t)tokid * E + c];
    float4 p = *(const float4*)&pos[(size_t)s * E + c];
    float4 o; o.x = a.x + p.x; o.y = a.y + p.y; o.z = a.z + p.z; o.w = a.w + p.w;
    *(float4*)&x[(size_t)t * E + c] = o;
}

// ---------------------------------------------------------------- layernorm
__global__ __launch_bounds__(256) void ln_kernel(const float* __restrict__ x,
                                                 const float* __restrict__ w,
                                                 const float* __restrict__ b,
                                                 us* __restrict__ out) {
    int row = blockIdx.x;
    int tid = threadIdx.x;
    int c = tid * 4;
    float4 v = *(const float4*)&x[(size_t)row * E + c];
    float s  = v.x + v.y + v.z + v.w;
    float sq = v.x * v.x + v.y * v.y + v.z * v.z + v.w * v.w;
    __shared__ float red[8];
    for (int o = 32; o > 0; o >>= 1) { s += __shfl_xor(s, o); sq += __shfl_xor(sq, o); }
    int wave = tid >> 6, lane = tid & 63;
    if (lane == 0) { red[wave] = s; red[4 + wave] = sq; }
    __syncthreads();
    if (tid == 0) {
        red[0] = red[0] + red[1] + red[2] + red[3];
        red[4] = red[4] + red[5] + red[6] + red[7];
    }
    __syncthreads();
    float mean = red[0] * (1.0f / E);
    float var  = red[4] * (1.0f / E) - mean * mean;
    float rstd = rsqrtf(var + 1e-5f);
    float4 wv = *(const float4*)&w[c];
    float4 bv = *(const float4*)&b[c];
    unsigned a0 = f2bf((v.x - mean) * rstd * wv.x + bv.x);
    unsigned a1 = f2bf((v.y - mean) * rstd * wv.y + bv.y);
    unsigned a2 = f2bf((v.z - mean) * rstd * wv.z + bv.z);
    unsigned a3 = f2bf((v.w - mean) * rstd * wv.w + bv.w);
    uint2 o; o.x = a0 | (a1 << 16); o.y = a2 | (a3 << 16);
    *(uint2*)&out[(size_t)row * E + c] = o;
}

// ---------------------------------------------------------------- GEMM m97-structure, BK=64 (two 32-wide LDS subtiles)
// C = A(bf16 [M][lda]) * Bw(bf16 [N][ldb])^T
// SPLITK: grid doubles, kz in {0,1} handles K-half, writes bf16 partial to outp + kz*M*ldo.
template <int OUT_BF16, int ACT_GELU, int HAS_BIAS, int HAS_RES, int SPLITK>
__global__ __launch_bounds__(256) void gemm_bf16(const us* __restrict__ A, int lda,
                                                 const us* __restrict__ Bw, int ldb,
                                                 const float* __restrict__ bias,
                                                 const float* __restrict__ res,
                                                 void* __restrict__ outp,
                                                 int M, int N, int K, int ldo) {
    __shared__ us As[2 * 128 * 32];   // [ks][128][32]
    __shared__ us Bs[2 * 128 * 32];
    int tid = threadIdx.x;
    int nwg = gridDim.x;
    int chunk = nwg >> 3;
    int wgid = blockIdx.x;
    int sw = (wgid & 7) * chunk + (wgid >> 3);   // bijective XCD swizzle (nwg%8==0)

    int bm, bn;
    us* outb = (us*)outp;
    float* outf = (float*)outp;
    if (SPLITK) {
        int kz = sw >> 8;          // 512 blocks: 256 tiles x 2 K-halves
        int rem = sw & 255;
        bm = (rem & 31) * 128;     // M fastest (MB=32)
        bn = (rem >> 5) * 128;
        A  += (size_t)kz * K;      // K = per-chunk K
        Bw += (size_t)kz * K;
        outb += (size_t)kz * M * ldo;
    } else {
        int MB = M >> 7;
        bm = (sw % MB) * 128;
        bn = (sw / MB) * 128;
    }

    int wave = tid >> 6, lane = tid & 63;
    int wr = wave >> 1, wc = wave & 1;
    int l15 = lane & 15, g4 = lane >> 4;
    f32x4 acc[4][4] = {};

    for (int k0 = 0; k0 < K; k0 += 64) {
        #pragma unroll
        for (int p4 = 0; p4 < 4; p4++) {
            int p = p4 * 256 + tid;               // 16B-chunk index 0..1023
            int ks = p >> 9, q = p & 511;
            int row = q >> 2, c8 = (q & 3) * 8;
            gld16(&A[(size_t)(bm + row) * lda + k0 + ks * 32 + c8], &As[p * 8]);
            gld16(&Bw[(size_t)(bn + row) * ldb + k0 + ks * 32 + c8], &Bs[p * 8]);
        }
        __syncthreads();
        bf16x8 a[4][2], bfr[4][2];
        #pragma unroll
        for (int m = 0; m < 4; m++)
            #pragma unroll
            for (int ks = 0; ks < 2; ks++)
                a[m][ks] = *(const bf16x8*)&As[ks * 4096 + (wr * 64 + m * 16 + l15) * 32 + g4 * 8];
        #pragma unroll
        for (int n = 0; n < 4; n++)
            #pragma unroll
            for (int ks = 0; ks < 2; ks++)
                bfr[n][ks] = *(const bf16x8*)&Bs[ks * 4096 + (wc * 64 + n * 16 + l15) * 32 + g4 * 8];
        #pragma unroll
        for (int m = 0; m < 4; m++)
            #pragma unroll
            for (int n = 0; n < 4; n++)
                #pragma unroll
                for (int ks = 0; ks < 2; ks++)
                    acc[m][n] = __builtin_amdgcn_mfma_f32_16x16x32_bf16(a[m][ks], bfr[n][ks], acc[m][n], 0, 0, 0);
        __syncthreads();
    }

    #pragma unroll
    for (int m = 0; m < 4; m++)
        #pragma unroll
        for (int n = 0; n < 4; n++)
            #pragma unroll
            for (int j = 0; j < 4; j++) {
                int r = bm + wr * 64 + m * 16 + g4 * 4 + j;
                int c = bn + wc * 64 + n * 16 + l15;
                float v = acc[m][n][j];
                if (HAS_BIAS) v += bias[c];
                if (ACT_GELU) v = 0.5f * v * (1.0f + erff(v * 0.70710678118f));
                if (HAS_RES) v += res[(size_t)r * ldo + c];
                if (OUT_BF16) outb[(size_t)r * ldo + c] = f2bf(v);
                else outf[(size_t)r * ldo + c] = v;
            }
}

// ---------------------------------------------------------------- ff2 combine: x += p0 + p1 + bias
__global__ __launch_bounds__(256) void combine_ff2(const us* __restrict__ p0,
                                                   const us* __restrict__ p1,
                                                   const float* __restrict__ bias,
                                                   float* __restrict__ x) {
    int g = blockIdx.x * 256 + threadIdx.x;      // 524288 threads, 8 elems each
    size_t base = (size_t)g * 8;
    int col = (int)(base & (E - 1));
    uint4 a = *(const uint4*)&p0[base];
    uint4 b = *(const uint4*)&p1[base];
    const us* pa = (const us*)&a;
    const us* pb = (const us*)&b;
    float4 x0 = *(const float4*)&x[base];
    float4 x1 = *(const float4*)&x[base + 4];
    float4 w0 = *(const float4*)&bias[col];
    float4 w1 = *(const float4*)&bias[col + 4];
    x0.x += bf2f(pa[0]) + bf2f(pb[0]) + w0.x;
    x0.y += bf2f(pa[1]) + bf2f(pb[1]) + w0.y;
    x0.z += bf2f(pa[2]) + bf2f(pb[2]) + w0.z;
    x0.w += bf2f(pa[3]) + bf2f(pb[3]) + w0.w;
    x1.x += bf2f(pa[4]) + bf2f(pb[4]) + w1.x;
    x1.y += bf2f(pa[5]) + bf2f(pb[5]) + w1.y;
    x1.z += bf2f(pa[6]) + bf2f(pb[6]) + w1.z;
    x1.w += bf2f(pa[7]) + bf2f(pb[7]) + w1.w;
    *(float4*)&x[base] = x0;
    *(float4*)&x[base + 4] = x1;
}

// ---------------------------------------------------------------- V transpose
__global__ __launch_bounds__(256) void transpose_v(const us* __restrict__ qkv,
                                                   us* __restrict__ vT) {
    int kt = blockIdx.x, h = blockIdx.y, b = blockIdx.z;
    int tid = threadIdx.x;
    __shared__ us T[64][72];
    const size_t base = (size_t)b * S * 3072 + 2048 + h * 64;
    int k0 = kt * 64;
    #pragma unroll
    for (int it = 0; it < 2; it++) {
        int p = tid + it * 256;
        int key = p & 63, c8 = (p >> 6) * 8;
        uint4 v = *(const uint4*)&qkv[base + (size_t)(k0 + key) * 3072 + c8];
        us* pv = (us*)&v;
        #pragma unroll
        for (int e = 0; e < 8; e++) T[c8 + e][key] = pv[e];
    }
    __syncthreads();
    const size_t obase = ((size_t)(b * H + h) * 64) * S + k0;
    #pragma unroll
    for (int it = 0; it < 2; it++) {
        int o = tid + it * 256;
        int d = o >> 3, cc = (o & 7) * 8;
        uint4 v = *(const uint4*)&T[d][cc];
        *(uint4*)&vT[obase + (size_t)d * S + cc] = v;
    }
}

// ---------------------------------------------------------------- flash attention: 8 waves, QBLK=128, KVB=64
__global__ __launch_bounds__(512, 4) void attn_kernel(const us* __restrict__ qkv,
                                                      const us* __restrict__ vT,
                                                      float* __restrict__ x) {
    int qt = blockIdx.x, h = blockIdx.y, b = blockIdx.z;
    int tid = threadIdx.x;
    int w = tid >> 6, lane = tid & 63;
    int l15 = lane & 15, g4 = lane >> 4;
    int s0 = qt * 128;
    int qrow_base = s0 + w * 16;
    const size_t qbase = (size_t)b * S * 3072;
    const size_t vtbase = ((size_t)(b * H + h) * 64) * S;

    __shared__ us K_lds[2][64 * 64];
    __shared__ us VT_lds[2][64 * 64];
    __shared__ us P_lds[8][16 * 72];

    bf16x8 q[2];
    #pragma unroll
    for (int dc = 0; dc < 2; dc++)
        q[dc] = *(const bf16x8*)&qkv[qbase + (size_t)(qrow_base + l15) * 3072 + h * 64 + dc * 32 + 8 * g4];

    f32x4 O[4] = {};
    float m_run[4], l_run[4];
    #pragma unroll
    for (int j = 0; j < 4; j++) { m_run[j] = -INFINITY; l_run[j] = 0.0f; }

    int lastt = 2 * qt + 1;
    {
        int p = tid, row = p >> 3, cc = p & 7;
        int scc = cc ^ (row & 7);
        gld16(&qkv[qbase + (size_t)(0 + row) * 3072 + 1024 + h * 64 + scc * 8], &K_lds[0][p * 8]);
        gld16(&vT[vtbase + (size_t)row * S + 0 + scc * 8], &VT_lds[0][p * 8]);
    }
    __syncthreads();

    for (int t = 0; t <= lastt; t++) {
        int bb = t & 1;
        if (t < lastt) {
            int p = tid, row = p >> 3, cc = p & 7;
            int scc = cc ^ (row & 7);
            gld16(&qkv[qbase + (size_t)((t + 1) * 64 + row) * 3072 + 1024 + h * 64 + scc * 8], &K_lds[bb ^ 1][p * 8]);
            gld16(&vT[vtbase + (size_t)row * S + (t + 1) * 64 + scc * 8], &VT_lds[bb ^ 1][p * 8]);
        }
        int k0 = t * 64;
        if (k0 <= qrow_base + 15) {
            f32x4 sf[4];
            __builtin_amdgcn_s_setprio(1);
            #pragma unroll
            for (int c = 0; c < 4; c++) {
                f32x4 z = {};
                int row = c * 16 + l15;
                #pragma unroll
                for (int dc = 0; dc < 2; dc++) {
                    int ch = (dc * 4 + g4) ^ (row & 7);
                    bf16x8 kb = *(const bf16x8*)&K_lds[bb][row * 64 + ch * 8];
                    z = __builtin_amdgcn_mfma_f32_16x16x32_bf16(q[dc], kb, z, 0, 0, 0);
                }
                sf[c] = z;
            }
            __builtin_amdgcn_s_setprio(0);
            bool needmask = (k0 + 63 > qrow_base);
            float pr[4][4], alpha[4];
            #pragma unroll
            for (int j = 0; j < 4; j++) {
                int qrow = qrow_base + g4 * 4 + j;
                float v0 = sf[0][j] * 0.125f, v1 = sf[1][j] * 0.125f;
                float v2 = sf[2][j] * 0.125f, v3 = sf[3][j] * 0.125f;
                if (needmask) {
                    if (k0 +      l15 > qrow) v0 = -INFINITY;
                    if (k0 + 16 + l15 > qrow) v1 = -INFINITY;
                    if (k0 + 32 + l15 > qrow) v2 = -INFINITY;
                    if (k0 + 48 + l15 > qrow) v3 = -INFINITY;
                }
                float tm = fmaxf(fmaxf(v0, v1), fmaxf(v2, v3));
                tm = fmaxf(tm, __shfl_xor(tm, 1, 16));
                tm = fmaxf(tm, __shfl_xor(tm, 2, 16));
                tm = fmaxf(tm, __shfl_xor(tm, 4, 16));
                tm = fmaxf(tm, __shfl_xor(tm, 8, 16));
                float mnew = fmaxf(m_run[j], tm);
                float p0 = __expf(v0 - mnew), p1 = __expf(v1 - mnew);
                float p2 = __expf(v2 - mnew), p3 = __expf(v3 - mnew);
                float ts = (p0 + p1) + (p2 + p3);
                ts += __shfl_xor(ts, 1, 16);
                ts += __shfl_xor(ts, 2, 16);
                ts += __shfl_xor(ts, 4, 16);
                ts += __shfl_xor(ts, 8, 16);
                alpha[j] = __expf(m_run[j] - mnew);
                l_run[j] = l_run[j] * alpha[j] + ts;
                m_run[j] = mnew;
                pr[0][j] = p0; pr[1][j] = p1; pr[2][j] = p2; pr[3][j] = p3;
            }
            #pragma unroll
            for (int f = 0; f < 4; f++)
                #pragma unroll
                for (int j = 0; j < 4; j++) O[f][j] *= alpha[j];
            us* Pw = &P_lds[w][0];
            #pragma unroll
            for (int c = 0; c < 4; c++)
                #pragma unroll
                for (int j = 0; j < 4; j++)
                    Pw[(g4 * 4 + j) * 72 + c * 16 + l15] = f2bf(pr[c][j]);
            __builtin_amdgcn_s_setprio(1);
            #pragma unroll
            for (int kc = 0; kc < 2; kc++) {
                bf16x8 pa = *(const bf16x8*)&Pw[l15 * 72 + kc * 32 + g4 * 8];
                #pragma unroll
                for (int dt = 0; dt < 4; dt++) {
                    int row = dt * 16 + l15;
                    int ch = (kc * 4 + g4) ^ (row & 7);
                    bf16x8 vb = *(const bf16x8*)&VT_lds[bb][row * 64 + ch * 8];
                    O[dt] = __builtin_amdgcn_mfma_f32_16x16x32_bf16(pa, vb, O[dt], 0, 0, 0);
                }
            }
            __builtin_amdgcn_s_setprio(0);
        }
        __syncthreads();
    }
    #pragma unroll
    for (int dt = 0; dt < 4; dt++)
        #pragma unroll
        for (int j = 0; j < 4; j++) {
            size_t o = ((size_t)b * S + qrow_base + g4 * 4 + j) * E + h * 64 + dt * 16 + l15;
            x[o] += O[dt][j] / l_run[j];
        }
}

// ---------------------------------------------------------------- launch
extern "C" void kernel_launch(void* const* d_in, const int* in_sizes, int n_in,
                              void* d_out, int out_size, void* d_ws, size_t ws_size,
                              hipStream_t stream) {
    const int*   idx    = (const int*)d_in[0];
    const float* tok    = (const float*)d_in[1];
    const float* pos    = (const float*)d_in[2];
    const float* qkv_w  = (const float*)d_in[3];
    const float* qkv_b  = (const float*)d_in[4];
    const float* ln1_w  = (const float*)d_in[5];
    const float* ln1_b  = (const float*)d_in[6];
    const float* ln2_w  = (const float*)d_in[7];
    const float* ln2_b  = (const float*)d_in[8];
    const float* ff1_w  = (const float*)d_in[9];
    const float* ff1_b  = (const float*)d_in[10];
    const float* ff2_w  = (const float*)d_in[11];
    const float* ff2_b  = (const float*)d_in[12];
    const float* fin_w  = (const float*)d_in[13];
    const float* fin_b  = (const float*)d_in[14];
    const float* proj_w = (const float*)d_in[15];

    char* ws = (char*)d_ws;
    float* x    = (float*)ws;                          // 16.78 MB f32 residual
    us*    xn   = (us*)(ws + 16777216);                // 8.39 MB bf16 LN out
    us*    qkvb = (us*)(ws + 25165824);                // 25.17 MB bf16 qkv / ff2 partials
    us*    hbuf = (us*)(ws + 50331648);                // 33.55 MB bf16 ff hidden
    us*    wbuf = (us*)(ws + 83886080);                // 8.39 MB bf16 per-layer weights
    us*    vTb  = (us*)(ws + 92274688);                // 8.39 MB bf16 V^T
    us*    pbuf = qkvb;                                // proj weight half reuses qkvb+hbuf space

    embed_kernel<<<NTOK, 256, 0, stream>>>(idx, tok, pos, x);
    for (int l = 0; l < DEPTH; l++) {
        ln_kernel<<<NTOK, 256, 0, stream>>>(x, ln1_w + l * E, ln1_b + l * E, xn);
        cast_kernel<<<1536, 256, 0, stream>>>(qkv_w + (size_t)l * 3 * E * E, wbuf, 3 * E * E / 8);
        gemm_bf16<1, 0, 1, 0, 0><<<768, 256, 0, stream>>>(
            xn, E, wbuf, E, qkv_b + l * 3 * E, nullptr, qkvb, NTOK, 3 * E, E, 3 * E);
        transpose_v<<<dim3(S / 64, H, BB), 256, 0, stream>>>(qkvb, vTb);
        attn_kernel<<<dim3(S / 128, H, BB), 512, 0, stream>>>(qkvb, vTb, x);
        ln_kernel<<<NTOK, 256, 0, stream>>>(x, ln2_w + l * E, ln2_b + l * E, xn);
        cast_kernel<<<2048, 256, 0, stream>>>(ff1_w + (size_t)l * 4 * E * E, wbuf, 4 * E * E / 8);
        gemm_bf16<1, 1, 1, 0, 0><<<1024, 256, 0, stream>>>(
            xn, E, wbuf, E, ff1_b + l * 4 * E, nullptr, hbuf, NTOK, 4 * E, E, 4 * E);
        cast_kernel<<<2048, 256, 0, stream>>>(ff2_w + (size_t)l * E * 4 * E, wbuf, 4 * E * E / 8);
        // split-K ff2: 512 blocks, bf16 partials into qkvb[0], qkvb[1]
        gemm_bf16<1, 0, 0, 0, 1><<<512, 256, 0, stream>>>(
            hbuf, 4 * E, wbuf, 4 * E, nullptr, nullptr, qkvb, NTOK, E, 2 * E, E);
        combine_ff2<<<2048, 256, 0, stream>>>(qkvb, qkvb + (size_t)NTOK * E, ff2_b + l * E, x);
    }
    ln_kernel<<<NTOK, 256, 0, stream>>>(x, fin_w, fin_b, xn);
    for (int hf = 0; hf < 2; hf++) {
        cast_kernel<<<8000, 256, 0, stream>>>(proj_w + (size_t)hf * 16000 * E, pbuf, 16000 * E / 8);
        gemm_bf16<0, 0, 0, 0, 0><<<4000, 256, 0, stream>>>(
            xn, E, pbuf, E, nullptr, nullptr, (float*)d_out + hf * 16000, NTOK, 16000, E, V);
    }
}

// Round 5
// 1982.115 us; speedup vs baseline: 2.3775x; 1.1052x over previous
//
#include <hip/hip_runtime.h>
#include <hip/hip_bf16.h>

#define DEPTH 6
#define E 1024
#define H 16
#define S 2048
#define V 32000
#define BB 2
#define HD 64
#define NTOK (BB * S)  // 4096

typedef __attribute__((ext_vector_type(8))) short bf16x8;
typedef __attribute__((ext_vector_type(4))) float f32x4;
typedef unsigned short us;

__device__ inline us f2bf(float f) {
    union { float f; unsigned u; } v; v.f = f;
    unsigned r = v.u + 0x7fff + ((v.u >> 16) & 1);
    return (us)(r >> 16);
}
__device__ inline float bf2f(us b) {
    union { unsigned u; float f; } v; v.u = ((unsigned)b) << 16;
    return v.f;
}

__device__ __forceinline__ void gld16(const us* g, us* l) {
    __builtin_amdgcn_global_load_lds(
        (const __attribute__((address_space(1))) unsigned int*)g,
        (__attribute__((address_space(3))) unsigned int*)l, 16, 0, 0);
}

// ---------------------------------------------------------------- f32 -> bf16 cast
__global__ __launch_bounds__(256) void cast_kernel(const float* __restrict__ in,
                                                   us* __restrict__ out, int n8) {
    int i = blockIdx.x * 256 + threadIdx.x;
    if (i >= n8) return;
    const float4* p = (const float4*)in + 2 * (size_t)i;
    float4 a = p[0], b = p[1];
    uint4 o;
    o.x = f2bf(a.x) | ((unsigned)f2bf(a.y) << 16);
    o.y = f2bf(a.z) | ((unsigned)f2bf(a.w) << 16);
    o.z = f2bf(b.x) | ((unsigned)f2bf(b.y) << 16);
    o.w = f2bf(b.z) | ((unsigned)f2bf(b.w) << 16);
    ((uint4*)out)[i] = o;
}

// ---------------------------------------------------------------- embedding
__global__ void embed_kernel(const int* __restrict__ idx, const float* __restrict__ tok,
                             const float* __restrict__ pos, float* __restrict__ x) {
    int t = blockIdx.x;
    int s = t & (S - 1);
    int tokid = idx[t];
    int c = threadIdx.x * 4;
    float4 a = *(const float4*)&tok[(size_t)tokid * E + c];
    float4 p = *(const float4*)&pos[(size_t)s * E + c];
    float4 o; o.x = a.x + p.x; o.y = a.y + p.y; o.z = a.z + p.z; o.w = a.w + p.w;
    *(float4*)&x[(size_t)t * E + c] = o;
}

// ---------------------------------------------------------------- layernorm
__global__ __launch_bounds__(256) void ln_kernel(const float* __restrict__ x,
                                                 const float* __restrict__ w,
                                                 const float* __restrict__ b,
                                                 us* __restrict__ out) {
    int row = blockIdx.x;
    int tid = threadIdx.x;
    int c = tid * 4;
    float4 v = *(const float4*)&x[(size_t)row * E + c];
    float s  = v.x + v.y + v.z + v.w;
    float sq = v.x * v.x + v.y * v.y + v.z * v.z + v.w * v.w;
    __shared__ float red[8];
    for (int o = 32; o > 0; o >>= 1) { s += __shfl_xor(s, o); sq += __shfl_xor(sq, o); }
    int wave = tid >> 6, lane = tid & 63;
    if (lane == 0) { red[wave] = s; red[4 + wave] = sq; }
    __syncthreads();
    if (tid == 0) {
        red[0] = red[0] + red[1] + red[2] + red[3];
        red[4] = red[4] + red[5] + red[6] + red[7];
    }
    __syncthreads();
    float mean = red[0] * (1.0f / E);
    float var  = red[4] * (1.0f / E) - mean * mean;
    float rstd = rsqrtf(var + 1e-5f);
    float4 wv = *(const float4*)&w[c];
    float4 bv = *(const float4*)&b[c];
    unsigned a0 = f2bf((v.x - mean) * rstd * wv.x + bv.x);
    unsigned a1 = f2bf((v.y - mean) * rstd * wv.y + bv.y);
    unsigned a2 = f2bf((v.z - mean) * rstd * wv.z + bv.z);
    unsigned a3 = f2bf((v.w - mean) * rstd * wv.w + bv.w);
    uint2 o; o.x = a0 | (a1 << 16); o.y = a2 | (a3 << 16);
    *(uint2*)&out[(size_t)row * E + c] = o;
}

// ================================================================ 256x256 8-phase GEMM (T2+T3+T4+T5)
// C = A(bf16 [M][lda]) * Bw(bf16 [N][ldb])^T. K%128==0, M%256==0, N%256==0, grid%8==0.
// 8 waves (2M x 4N), BK=64, 128KiB LDS double-buffered, 1 half-tile staged/phase,
// counted vmcnt(6) at phases 4/8 only. LDS granule XOR-swizzle on stage-src and read.
#define GPH(dd, fb, STAGE, ISVM, IS12)                                              \
  {                                                                                 \
    bf16x8 afr0[2], afr1[2];                                                        \
    if ((fb) == 0) {                                                                \
      _Pragma("unroll")                                                             \
      for (int n = 0; n < 4; n++)                                                   \
        _Pragma("unroll")                                                           \
        for (int ks = 0; ks < 2; ks++)                                              \
          bfr[n][ks] = *(const bf16x8*)&lds[32768 + (dd) * 16384 +                  \
              (brow + n * 16) * 64 + ((ks * 4 + g4) ^ xg) * 8];                     \
    }                                                                               \
    _Pragma("unroll")                                                               \
    for (int ks = 0; ks < 2; ks++) {                                                \
      afr0[ks] = *(const bf16x8*)&lds[(dd) * 16384 + ((fb) >> 1) * 4096 +           \
          arow0 * 64 + ((ks * 4 + g4) ^ xg) * 8];                                   \
      afr1[ks] = *(const bf16x8*)&lds[(dd) * 16384 + ((fb) >> 1) * 4096 +           \
          arow1 * 64 + ((ks * 4 + g4) ^ xg) * 8];                                   \
    }                                                                               \
    STAGE;                                                                          \
    __builtin_amdgcn_sched_barrier(0);                                              \
    if (IS12) asm volatile("s_waitcnt lgkmcnt(8)" ::: "memory");                    \
    __builtin_amdgcn_s_barrier();                                                   \
    asm volatile("s_waitcnt lgkmcnt(0)" ::: "memory");                              \
    __builtin_amdgcn_sched_barrier(0);                                              \
    __builtin_amdgcn_s_setprio(1);                                                  \
    _Pragma("unroll")                                                               \
    for (int n = 0; n < 4; n++)                                                     \
      _Pragma("unroll")                                                             \
      for (int ks = 0; ks < 2; ks++) {                                              \
        acc[(fb)][n]     = __builtin_amdgcn_mfma_f32_16x16x32_bf16(afr0[ks], bfr[n][ks], acc[(fb)][n], 0, 0, 0);     \
        acc[(fb) + 1][n] = __builtin_amdgcn_mfma_f32_16x16x32_bf16(afr1[ks], bfr[n][ks], acc[(fb) + 1][n], 0, 0, 0); \
      }                                                                             \
    __builtin_amdgcn_s_setprio(0);                                                  \
    __builtin_amdgcn_sched_barrier(0);                                              \
    if (ISVM) asm volatile("s_waitcnt vmcnt(6)" ::: "memory");                      \
    __builtin_amdgcn_s_barrier();                                                   \
  }

template <int OUT_BF16, int ACT_GELU, int HAS_BIAS>
__global__ __launch_bounds__(512, 2) void gemm256(const us* __restrict__ A, int lda,
                                                  const us* __restrict__ Bw, int ldb,
                                                  const float* __restrict__ bias,
                                                  void* __restrict__ outp,
                                                  int M, int N, int K, int ldo) {
    // LDS layout (us elems): A: [2 dbuf][4 regions][64 rows][64 cols] = 0..32767
    //                        B: [2 dbuf][256 rows][64 cols] = 32768..65535
    // A region q holds tile rows {q*32..q*32+31} (wr=0 local rows 0-31)
    //                        and {128+q*32..+31} (wr=1 local rows 32-63).
    __shared__ us lds[65536];
    int tid = threadIdx.x;
    int nwg = gridDim.x;
    int wgid = blockIdx.x;
    int chunk = nwg >> 3;
    int sw = (wgid & 7) * chunk + (wgid >> 3);   // bijective XCD swizzle
    int MB = M >> 8;
    int bm = (sw % MB) * 256;                    // M-fastest: share B-panel within XCD
    int bn = (sw / MB) * 256;
    int w = tid >> 6, lane = tid & 63;
    int wr = w >> 2, wc = w & 3;
    int l15 = lane & 15, g4 = lane >> 4;
    int xg = l15 & 7;
    int arow0 = (wr ? 32 : 0) + l15;
    int arow1 = arow0 + 16;
    int brow = wc * 64 + l15;
    int NT = K >> 6;

    f32x4 acc[8][4] = {};
    bf16x8 bfr[4][2];

    auto stA = [&](int u, int dd, int h) {   // stage A half-tile (regions 2h,2h+1) of tile u
        int uu = (u < NT) ? u : NT - 1;      // tail: wrap (keeps vmcnt FIFO exact, region dead)
        #pragma unroll
        for (int i = 0; i < 2; i++) {
            int k = tid + i * 512;
            int q = 2 * h + (k >> 9);
            int r = (k >> 3) & 63;
            int tr = q * 32 + (r & 31) + ((r >> 5) << 7);
            int gp = (k & 7) ^ (r & 7);      // inverse swizzle on global source
            gld16(A + (size_t)(bm + tr) * lda + uu * 64 + gp * 8,
                  &lds[dd * 16384 + h * 8192 + k * 8]);
        }
    };
    auto stB = [&](int u, int dd, int h) {   // stage B half-tile (N-rows h*128..+127) of tile u
        int uu = (u < NT) ? u : NT - 1;
        #pragma unroll
        for (int i = 0; i < 2; i++) {
            int k = tid + i * 512;
            int row = h * 128 + (k >> 3);
            int gp = (k & 7) ^ ((k >> 3) & 7);
            gld16(Bw + (size_t)(bn + row) * ldb + uu * 64 + gp * 8,
                  &lds[32768 + dd * 16384 + h * 8192 + k * 8]);
        }
    };

    // prologue: t0 full + t1.B + t1.Ah0 (7 half-tiles, 14 loads); wait all t0 (6 left in flight)
    stB(0, 0, 0); stB(0, 0, 1); stA(0, 0, 0); stA(0, 0, 1);
    stB(1, 1, 0); stB(1, 1, 1); stA(1, 1, 0);
    __builtin_amdgcn_sched_barrier(0);
    asm volatile("s_waitcnt vmcnt(6)" ::: "memory");
    __builtin_amdgcn_s_barrier();

    #pragma unroll 1
    for (int t = 0; t < NT; t += 2) {        // even tiles -> buf0, odd -> buf1
        GPH(0, 0, stA(t + 1, 1, 1), 0, 1)    // P1: compute t f0-1 | stage (t+1).Ah1
        GPH(0, 2, stB(t + 2, 0, 0), 0, 0)    // P2
        GPH(0, 4, stB(t + 2, 0, 1), 0, 0)    // P3
        GPH(0, 6, stA(t + 2, 0, 0), 1, 0)    // P4: vmcnt(6) -> t+1 fully landed
        GPH(1, 0, stA(t + 2, 0, 1), 0, 1)    // P5: compute t+1
        GPH(1, 2, stB(t + 3, 1, 0), 0, 0)    // P6
        GPH(1, 4, stB(t + 3, 1, 1), 0, 0)    // P7
        GPH(1, 6, stA(t + 3, 1, 0), 1, 0)    // P8: vmcnt(6) -> t+2 fully landed
    }

    float* outf = (float*)outp;
    us* outb = (us*)outp;
    #pragma unroll
    for (int mf = 0; mf < 8; mf++)
        #pragma unroll
        for (int n = 0; n < 4; n++)
            #pragma unroll
            for (int j = 0; j < 4; j++) {
                int r = bm + wr * 128 + mf * 16 + g4 * 4 + j;
                int c = bn + wc * 64 + n * 16 + l15;
                float v = acc[mf][n][j];
                if (HAS_BIAS) v += bias[c];
                if (ACT_GELU) v = 0.5f * v * (1.0f + erff(v * 0.70710678118f));
                if (OUT_BF16) outb[(size_t)r * ldo + c] = f2bf(v);
                else outf[(size_t)r * ldo + c] = v;
            }
}

// ---------------------------------------------------------------- 128^2 split-K GEMM (ff2 only)
template <int SPLITK>
__global__ __launch_bounds__(256) void gemm_bf16(const us* __restrict__ A, int lda,
                                                 const us* __restrict__ Bw, int ldb,
                                                 void* __restrict__ outp,
                                                 int M, int N, int K, int ldo) {
    __shared__ us As[2 * 128 * 32];
    __shared__ us Bs[2 * 128 * 32];
    int tid = threadIdx.x;
    int nwg = gridDim.x;
    int chunk = nwg >> 3;
    int wgid = blockIdx.x;
    int sw = (wgid & 7) * chunk + (wgid >> 3);

    int bm, bn;
    us* outb = (us*)outp;
    {
        int kz = sw >> 8;          // 512 blocks: 256 tiles x 2 K-halves
        int rem = sw & 255;
        bm = (rem & 31) * 128;
        bn = (rem >> 5) * 128;
        A  += (size_t)kz * K;
        Bw += (size_t)kz * K;
        outb += (size_t)kz * M * ldo;
    }

    int wave = tid >> 6, lane = tid & 63;
    int wr = wave >> 1, wc = wave & 1;
    int l15 = lane & 15, g4 = lane >> 4;
    f32x4 acc[4][4] = {};

    for (int k0 = 0; k0 < K; k0 += 64) {
        #pragma unroll
        for (int p4 = 0; p4 < 4; p4++) {
            int p = p4 * 256 + tid;
            int ks = p >> 9, q = p & 511;
            int row = q >> 2, c8 = (q & 3) * 8;
            gld16(&A[(size_t)(bm + row) * lda + k0 + ks * 32 + c8], &As[p * 8]);
            gld16(&Bw[(size_t)(bn + row) * ldb + k0 + ks * 32 + c8], &Bs[p * 8]);
        }
        __syncthreads();
        bf16x8 a[4][2], bfr[4][2];
        #pragma unroll
        for (int m = 0; m < 4; m++)
            #pragma unroll
            for (int ks = 0; ks < 2; ks++)
                a[m][ks] = *(const bf16x8*)&As[ks * 4096 + (wr * 64 + m * 16 + l15) * 32 + g4 * 8];
        #pragma unroll
        for (int n = 0; n < 4; n++)
            #pragma unroll
            for (int ks = 0; ks < 2; ks++)
                bfr[n][ks] = *(const bf16x8*)&Bs[ks * 4096 + (wc * 64 + n * 16 + l15) * 32 + g4 * 8];
        #pragma unroll
        for (int m = 0; m < 4; m++)
            #pragma unroll
            for (int n = 0; n < 4; n++)
                #pragma unroll
                for (int ks = 0; ks < 2; ks++)
                    acc[m][n] = __builtin_amdgcn_mfma_f32_16x16x32_bf16(a[m][ks], bfr[n][ks], acc[m][n], 0, 0, 0);
        __syncthreads();
    }

    #pragma unroll
    for (int m = 0; m < 4; m++)
        #pragma unroll
        for (int n = 0; n < 4; n++)
            #pragma unroll
            for (int j = 0; j < 4; j++) {
                int r = bm + wr * 64 + m * 16 + g4 * 4 + j;
                int c = bn + wc * 64 + n * 16 + l15;
                outb[(size_t)r * ldo + c] = f2bf(acc[m][n][j]);
            }
}

// ---------------------------------------------------------------- ff2 combine: x += p0 + p1 + bias
__global__ __launch_bounds__(256) void combine_ff2(const us* __restrict__ p0,
                                                   const us* __restrict__ p1,
                                                   const float* __restrict__ bias,
                                                   float* __restrict__ x) {
    int g = blockIdx.x * 256 + threadIdx.x;
    size_t base = (size_t)g * 8;
    int col = (int)(base & (E - 1));
    uint4 a = *(const uint4*)&p0[base];
    uint4 b = *(const uint4*)&p1[base];
    const us* pa = (const us*)&a;
    const us* pb = (const us*)&b;
    float4 x0 = *(const float4*)&x[base];
    float4 x1 = *(const float4*)&x[base + 4];
    float4 w0 = *(const float4*)&bias[col];
    float4 w1 = *(const float4*)&bias[col + 4];
    x0.x += bf2f(pa[0]) + bf2f(pb[0]) + w0.x;
    x0.y += bf2f(pa[1]) + bf2f(pb[1]) + w0.y;
    x0.z += bf2f(pa[2]) + bf2f(pb[2]) + w0.z;
    x0.w += bf2f(pa[3]) + bf2f(pb[3]) + w0.w;
    x1.x += bf2f(pa[4]) + bf2f(pb[4]) + w1.x;
    x1.y += bf2f(pa[5]) + bf2f(pb[5]) + w1.y;
    x1.z += bf2f(pa[6]) + bf2f(pb[6]) + w1.z;
    x1.w += bf2f(pa[7]) + bf2f(pb[7]) + w1.w;
    *(float4*)&x[base] = x0;
    *(float4*)&x[base + 4] = x1;
}

// ---------------------------------------------------------------- V transpose
__global__ __launch_bounds__(256) void transpose_v(const us* __restrict__ qkv,
                                                   us* __restrict__ vT) {
    int kt = blockIdx.x, h = blockIdx.y, b = blockIdx.z;
    int tid = threadIdx.x;
    __shared__ us T[64][72];
    const size_t base = (size_t)b * S * 3072 + 2048 + h * 64;
    int k0 = kt * 64;
    #pragma unroll
    for (int it = 0; it < 2; it++) {
        int p = tid + it * 256;
        int key = p & 63, c8 = (p >> 6) * 8;
        uint4 v = *(const uint4*)&qkv[base + (size_t)(k0 + key) * 3072 + c8];
        us* pv = (us*)&v;
        #pragma unroll
        for (int e = 0; e < 8; e++) T[c8 + e][key] = pv[e];
    }
    __syncthreads();
    const size_t obase = ((size_t)(b * H + h) * 64) * S + k0;
    #pragma unroll
    for (int it = 0; it < 2; it++) {
        int o = tid + it * 256;
        int d = o >> 3, cc = (o & 7) * 8;
        uint4 v = *(const uint4*)&T[d][cc];
        *(uint4*)&vT[obase + (size_t)d * S + cc] = v;
    }
}

// ---------------------------------------------------------------- flash attention: 8 waves, QBLK=128, KVB=64
__global__ __launch_bounds__(512, 4) void attn_kernel(const us* __restrict__ qkv,
                                                      const us* __restrict__ vT,
                                                      float* __restrict__ x) {
    int qt = blockIdx.x, h = blockIdx.y, b = blockIdx.z;
    int tid = threadIdx.x;
    int w = tid >> 6, lane = tid & 63;
    int l15 = lane & 15, g4 = lane >> 4;
    int s0 = qt * 128;
    int qrow_base = s0 + w * 16;
    const size_t qbase = (size_t)b * S * 3072;
    const size_t vtbase = ((size_t)(b * H + h) * 64) * S;

    __shared__ us K_lds[2][64 * 64];
    __shared__ us VT_lds[2][64 * 64];
    __shared__ us P_lds[8][16 * 72];

    bf16x8 q[2];
    #pragma unroll
    for (int dc = 0; dc < 2; dc++)
        q[dc] = *(const bf16x8*)&qkv[qbase + (size_t)(qrow_base + l15) * 3072 + h * 64 + dc * 32 + 8 * g4];

    f32x4 O[4] = {};
    float m_run[4], l_run[4];
    #pragma unroll
    for (int j = 0; j < 4; j++) { m_run[j] = -INFINITY; l_run[j] = 0.0f; }

    int lastt = 2 * qt + 1;
    {
        int p = tid, row = p >> 3, cc = p & 7;
        int scc = cc ^ (row & 7);
        gld16(&qkv[qbase + (size_t)(0 + row) * 3072 + 1024 + h * 64 + scc * 8], &K_lds[0][p * 8]);
        gld16(&vT[vtbase + (size_t)row * S + 0 + scc * 8], &VT_lds[0][p * 8]);
    }
    __syncthreads();

    for (int t = 0; t <= lastt; t++) {
        int bb = t & 1;
        if (t < lastt) {
            int p = tid, row = p >> 3, cc = p & 7;
            int scc = cc ^ (row & 7);
            gld16(&qkv[qbase + (size_t)((t + 1) * 64 + row) * 3072 + 1024 + h * 64 + scc * 8], &K_lds[bb ^ 1][p * 8]);
            gld16(&vT[vtbase + (size_t)row * S + (t + 1) * 64 + scc * 8], &VT_lds[bb ^ 1][p * 8]);
        }
        int k0 = t * 64;
        if (k0 <= qrow_base + 15) {
            f32x4 sf[4];
            __builtin_amdgcn_s_setprio(1);
            #pragma unroll
            for (int c = 0; c < 4; c++) {
                f32x4 z = {};
                int row = c * 16 + l15;
                #pragma unroll
                for (int dc = 0; dc < 2; dc++) {
                    int ch = (dc * 4 + g4) ^ (row & 7);
                    bf16x8 kb = *(const bf16x8*)&K_lds[bb][row * 64 + ch * 8];
                    z = __builtin_amdgcn_mfma_f32_16x16x32_bf16(q[dc], kb, z, 0, 0, 0);
                }
                sf[c] = z;
            }
            __builtin_amdgcn_s_setprio(0);
            bool needmask = (k0 + 63 > qrow_base);
            float pr[4][4], alpha[4];
            #pragma unroll
            for (int j = 0; j < 4; j++) {
                int qrow = qrow_base + g4 * 4 + j;
                float v0 = sf[0][j] * 0.125f, v1 = sf[1][j] * 0.125f;
                float v2 = sf[2][j] * 0.125f, v3 = sf[3][j] * 0.125f;
                if (needmask) {
                    if (k0 +      l15 > qrow) v0 = -INFINITY;
                    if (k0 + 16 + l15 > qrow) v1 = -INFINITY;
                    if (k0 + 32 + l15 > qrow) v2 = -INFINITY;
                    if (k0 + 48 + l15 > qrow) v3 = -INFINITY;
                }
                float tm = fmaxf(fmaxf(v0, v1), fmaxf(v2, v3));
                tm = fmaxf(tm, __shfl_xor(tm, 1, 16));
                tm = fmaxf(tm, __shfl_xor(tm, 2, 16));
                tm = fmaxf(tm, __shfl_xor(tm, 4, 16));
                tm = fmaxf(tm, __shfl_xor(tm, 8, 16));
                float mnew = fmaxf(m_run[j], tm);
                float p0 = __expf(v0 - mnew), p1 = __expf(v1 - mnew);
                float p2 = __expf(v2 - mnew), p3 = __expf(v3 - mnew);
                float ts = (p0 + p1) + (p2 + p3);
                ts += __shfl_xor(ts, 1, 16);
                ts += __shfl_xor(ts, 2, 16);
                ts += __shfl_xor(ts, 4, 16);
                ts += __shfl_xor(ts, 8, 16);
                alpha[j] = __expf(m_run[j] - mnew);
                l_run[j] = l_run[j] * alpha[j] + ts;
                m_run[j] = mnew;
                pr[0][j] = p0; pr[1][j] = p1; pr[2][j] = p2; pr[3][j] = p3;
            }
            #pragma unroll
            for (int f = 0; f < 4; f++)
                #pragma unroll
                for (int j = 0; j < 4; j++) O[f][j] *= alpha[j];
            us* Pw = &P_lds[w][0];
            #pragma unroll
            for (int c = 0; c < 4; c++)
                #pragma unroll
                for (int j = 0; j < 4; j++)
                    Pw[(g4 * 4 + j) * 72 + c * 16 + l15] = f2bf(pr[c][j]);
            __builtin_amdgcn_s_setprio(1);
            #pragma unroll
            for (int kc = 0; kc < 2; kc++) {
                bf16x8 pa = *(const bf16x8*)&Pw[l15 * 72 + kc * 32 + g4 * 8];
                #pragma unroll
                for (int dt = 0; dt < 4; dt++) {
                    int row = dt * 16 + l15;
                    int ch = (kc * 4 + g4) ^ (row & 7);
                    bf16x8 vb = *(const bf16x8*)&VT_lds[bb][row * 64 + ch * 8];
                    O[dt] = __builtin_amdgcn_mfma_f32_16x16x32_bf16(pa, vb, O[dt], 0, 0, 0);
                }
            }
            __builtin_amdgcn_s_setprio(0);
        }
        __syncthreads();
    }
    #pragma unroll
    for (int dt = 0; dt < 4; dt++)
        #pragma unroll
        for (int j = 0; j < 4; j++) {
            size_t o = ((size_t)b * S + qrow_base + g4 * 4 + j) * E + h * 64 + dt * 16 + l15;
            x[o] += O[dt][j] / l_run[j];
        }
}

// ---------------------------------------------------------------- launch
extern "C" void kernel_launch(void* const* d_in, const int* in_sizes, int n_in,
                              void* d_out, int out_size, void* d_ws, size_t ws_size,
                              hipStream_t stream) {
    const int*   idx    = (const int*)d_in[0];
    const float* tok    = (const float*)d_in[1];
    const float* pos    = (const float*)d_in[2];
    const float* qkv_w  = (const float*)d_in[3];
    const float* qkv_b  = (const float*)d_in[4];
    const float* ln1_w  = (const float*)d_in[5];
    const float* ln1_b  = (const float*)d_in[6];
    const float* ln2_w  = (const float*)d_in[7];
    const float* ln2_b  = (const float*)d_in[8];
    const float* ff1_w  = (const float*)d_in[9];
    const float* ff1_b  = (const float*)d_in[10];
    const float* ff2_w  = (const float*)d_in[11];
    const float* ff2_b  = (const float*)d_in[12];
    const float* fin_w  = (const float*)d_in[13];
    const float* fin_b  = (const float*)d_in[14];
    const float* proj_w = (const float*)d_in[15];

    char* ws = (char*)d_ws;
    float* x    = (float*)ws;                          // 16.78 MB f32 residual
    us*    xn   = (us*)(ws + 16777216);                // 8.39 MB bf16 LN out
    us*    qkvb = (us*)(ws + 25165824);                // 25.17 MB bf16 qkv / ff2 partials
    us*    hbuf = (us*)(ws + 50331648);                // 33.55 MB bf16 ff hidden
    us*    wbuf = (us*)(ws + 83886080);                // 8.39 MB bf16 per-layer weights
    us*    vTb  = (us*)(ws + 92274688);                // 8.39 MB bf16 V^T
    us*    pbuf = qkvb;                                // 65.5 MB proj weights (qkvb..wbuf span, free then)

    embed_kernel<<<NTOK, 256, 0, stream>>>(idx, tok, pos, x);
    for (int l = 0; l < DEPTH; l++) {
        ln_kernel<<<NTOK, 256, 0, stream>>>(x, ln1_w + l * E, ln1_b + l * E, xn);
        cast_kernel<<<1536, 256, 0, stream>>>(qkv_w + (size_t)l * 3 * E * E, wbuf, 3 * E * E / 8);
        gemm256<1, 0, 1><<<192, 512, 0, stream>>>(
            xn, E, wbuf, E, qkv_b + l * 3 * E, qkvb, NTOK, 3 * E, E, 3 * E);
        transpose_v<<<dim3(S / 64, H, BB), 256, 0, stream>>>(qkvb, vTb);
        attn_kernel<<<dim3(S / 128, H, BB), 512, 0, stream>>>(qkvb, vTb, x);
        ln_kernel<<<NTOK, 256, 0, stream>>>(x, ln2_w + l * E, ln2_b + l * E, xn);
        cast_kernel<<<2048, 256, 0, stream>>>(ff1_w + (size_t)l * 4 * E * E, wbuf, 4 * E * E / 8);
        gemm256<1, 1, 1><<<256, 512, 0, stream>>>(
            xn, E, wbuf, E, ff1_b + l * 4 * E, hbuf, NTOK, 4 * E, E, 4 * E);
        cast_kernel<<<2048, 256, 0, stream>>>(ff2_w + (size_t)l * E * 4 * E, wbuf, 4 * E * E / 8);
        gemm_bf16<1><<<512, 256, 0, stream>>>(
            hbuf, 4 * E, wbuf, 4 * E, qkvb, NTOK, E, 2 * E, E);
        combine_ff2<<<2048, 256, 0, stream>>>(qkvb, qkvb + (size_t)NTOK * E, ff2_b + l * E, x);
    }
    ln_kernel<<<NTOK, 256, 0, stream>>>(x, fin_w, fin_b, xn);
    cast_kernel<<<16000, 256, 0, stream>>>(proj_w, pbuf, V * E / 8);
    gemm256<0, 0, 0><<<2000, 512, 0, stream>>>(
        xn, E, pbuf, E, nullptr, d_out, NTOK, V, E, V);
}